// Round 4
// baseline (708.868 us; speedup 1.0000x reference)
//
#include <hip/hip_runtime.h>

__device__ __forceinline__ float sigf(float x){ return 1.0f/(1.0f+__expf(-x)); }
__device__ __forceinline__ float tanhfast(float x){ return 1.0f - 2.0f/(__expf(2.0f*x)+1.0f); }

#define Bn 16
#define Tn 128
#define Fn 40
#define Hn 64
#define Dn 80   // 2F
#define NHn 5
#define DKn 16
#define FFn 320

// ---- round-11 macros (rec5) ----
#define LD4(p,i) (((const float4*)(p))[i])
#define DECL8(v, p) \
  float4 v##0=LD4(p,0), v##1=LD4(p,1), v##2=LD4(p,2), v##3=LD4(p,3), \
         v##4=LD4(p,4), v##5=LD4(p,5), v##6=LD4(p,6), v##7=LD4(p,7);
#define PIN4(P) asm volatile("" : "+v"(P.x), "+v"(P.y), "+v"(P.z), "+v"(P.w));
#define PIN8(v) PIN4(v##0) PIN4(v##1) PIN4(v##2) PIN4(v##3) PIN4(v##4) PIN4(v##5) \
  PIN4(v##6) PIN4(v##7)
#define ACC8(base) \
  { const float4 h0=hb4[(base)+0]; a += h0.x*w0.x + h0.y*w0.y + h0.z*w0.z + h0.w*w0.w; } \
  { const float4 h1=hb4[(base)+1]; a += h1.x*w1.x + h1.y*w1.y + h1.z*w1.z + h1.w*w1.w; } \
  { const float4 h2=hb4[(base)+2]; a += h2.x*w2.x + h2.y*w2.y + h2.z*w2.z + h2.w*w2.w; } \
  { const float4 h3=hb4[(base)+3]; a += h3.x*w3.x + h3.y*w3.y + h3.z*w3.z + h3.w*w3.w; } \
  { const float4 h4=hb4[(base)+4]; a += h4.x*w4.x + h4.y*w4.y + h4.z*w4.z + h4.w*w4.w; } \
  { const float4 h5=hb4[(base)+5]; a += h5.x*w5.x + h5.y*w5.y + h5.z*w5.z + h5.w*w5.w; } \
  { const float4 h6=hb4[(base)+6]; a += h6.x*w6.x + h6.y*w6.y + h6.z*w6.z + h6.w*w6.w; } \
  { const float4 h7=hb4[(base)+7]; a += h7.x*w7.x + h7.y*w7.y + h7.z*w7.z + h7.w*w7.w; }

// ---------------- Stage A: per-feature LSTMs (rec5-structure port, round 13) ----------------
// Round-12's one-row-per-thread (64 pinned floats @256thr, lb(256,5)) made the
// allocator give up: VGPR_Count=48, weights spilled, WRITE_SIZE 0.3->5.4MB,
// 163->212us. Fix: use the PROVEN k_bilstm_rec5 register shape — 512 threads,
// thread owns gate row r = t&255 with HALF the H=64 dot (8 pinned float4),
// halves summed via pa[512] in LDS. Same numerics as round-6 (dot split in 2).
__global__ __launch_bounds__(512) void k_feat_lstm3(
    const float* __restrict__ x,
    const float* __restrict__ qWih, const float* __restrict__ qWhh, const float* __restrict__ qb,
    const float* __restrict__ kWih, const float* __restrict__ kWhh, const float* __restrict__ kb,
    const float* __restrict__ vWih, const float* __restrict__ vWhh, const float* __restrict__ vb,
    float* __restrict__ hq, float* __restrict__ hk, float* __restrict__ hv)
{
  const int blk = blockIdx.x;
  const int t = threadIdx.x;          // 0..511
  if (blk >= 1280){
    const int inst = (blk - 1280)*512 + t;      // 0..1023, guard to 640
    if (inst >= 640) return;
    const int bi = inst/Fn, f = inst%Fn;
    const float* xp = x + bi*Tn*Fn + f;
    const float wih0=vWih[0], wih1=vWih[1], wih2=vWih[2], wih3=vWih[3];
    const float u0=vWhh[0], u1=vWhh[1], u2=vWhh[2], u3=vWhh[3];
    const float c0=vb[0], c1=vb[1], c2=vb[2], c3=vb[3];
    float h=0.f, c=0.f;
    #pragma unroll 1
    for (int tt=0;tt<Tn;++tt){
      float xt = xp[tt*Fn];
      float zi = xt*wih0 + h*u0 + c0;
      float zf = xt*wih1 + h*u1 + c1;
      float zg = xt*wih2 + h*u2 + c2;
      float zo = xt*wih3 + h*u3 + c3;
      c = sigf(zf)*c + sigf(zi)*tanhfast(zg);
      h = sigf(zo)*tanhfast(c);
    }
    hv[inst] = h;
    return;
  }
  const bool isk = blk >= 640;
  const int inst = isk ? blk-640 : blk;         // 0..639
  const int bi = inst/Fn, f = inst%Fn;
  const float* Whh = isk ? kWhh : qWhh;
  const float* Wih = isk ? kWih : qWih;
  const float* bia = isk ? kb  : qb;
  float* outp = isk ? hk : hq;

  const int half = t >> 8;   // 0: h[0:32), 1: h[32:64)
  const int r    = t & 255;  // gate row (i,f,g,o stacked: 0-63 i, 64-127 f, 128-191 g, 192-255 o)
  DECL8(w, Whh + r*Hn + half*32);
  PIN8(w);
  const float wih0 = Wih[r];
  const float bb0  = bia[r];

  __shared__ __align__(16) float hb[Hn];
  __shared__ float pa[512];
  __shared__ float xls[Tn];

  const float* xp = x + bi*Tn*Fn + f;
  if (t < Tn) xls[t] = xp[t*Fn];        // stage all 128 timesteps
  if (t < Hn) hb[t] = 0.f;
  float c = 0.f, h = 0.f;
  __syncthreads();

  const float4* hb4 = (const float4*)hb;
  const int jbase = half*8;
  #pragma unroll 1
  for (int step=0; step<Tn; ++step){
    const float xt = xls[step];
    float a = half ? 0.f : (bb0 + xt*wih0);
    ACC8(jbase)
    pa[t] = a;
    __syncthreads();
    if (t < Hn){
      const float zi = pa[t    ] + pa[t+256];
      const float zf = pa[t+ 64] + pa[t+320];
      const float zg = pa[t+128] + pa[t+384];
      const float zo = pa[t+192] + pa[t+448];
      c = sigf(zf)*c + sigf(zi)*tanhfast(zg);
      h = sigf(zo)*tanhfast(c);
      hb[t] = h;
    }
    __syncthreads();
  }
  if (t < Hn) outp[inst*Hn + t] = h;
}

// ---------------- Stage B1: feature attention softmax (writes output b) ----------------
__global__ __launch_bounds__(64) void k_featattn(
    const float* __restrict__ hq, const float* __restrict__ hk, const float* __restrict__ hv,
    float* __restrict__ Wsm, float* __restrict__ out_b)
{
  const int blk = blockIdx.x;
  const int bi = blk / Fn, i = blk % Fn;
  const int j = threadIdx.x;
  __shared__ float qrow[Hn];
  qrow[j] = hq[blk*Hn + j];
  __syncthreads();
  float s = -1e30f;
  if (j < Fn){
    const float* krow = hk + (bi*Fn + j)*Hn;
    float a = 0.f;
    #pragma unroll
    for (int h2=0; h2<Hn; ++h2) a += qrow[h2]*krow[h2];
    s = a * 0.125f * hv[bi*Fn + j];
  }
  float m = s;
  #pragma unroll
  for (int off=32; off>0; off>>=1) m = fmaxf(m, __shfl_xor(m, off));
  float e = (j < Fn) ? __expf(s - m) : 0.f;
  float tot = e;
  #pragma unroll
  for (int off=32; off>0; off>>=1) tot += __shfl_xor(tot, off);
  float p = e / tot;
  if (j < Fn){
    Wsm[blk*Fn + j] = p;
    out_b[bi*(Fn*Fn) + j*Fn + i] = p;
  }
}

// ---------------- Stage B2: attn_output + src concat ----------------
__global__ __launch_bounds__(128) void k_build_src(
    const float* __restrict__ x, const float* __restrict__ Wsm, float* __restrict__ src)
{
  const int blk = blockIdx.x;
  const int bi = blk / Tn;
  const int tid = threadIdx.x;
  __shared__ float xrow[Fn];
  if (tid < Fn) xrow[tid] = x[blk*Fn + tid];
  __syncthreads();
  if (tid < Fn){
    src[blk*Dn + tid] = xrow[tid];
  } else if (tid < Dn){
    const int i = tid - Fn;
    const float* wrow = Wsm + (bi*Fn + i)*Fn;
    float a = 0.f;
    #pragma unroll
    for (int j2=0;j2<Fn;++j2) a += xrow[j2]*wrow[j2];
    src[blk*Dn + tid] = a;
  }
}

// ---------------- Transformer: qkv projection ----------------
__global__ __launch_bounds__(128) void k_qkv(
    const float* __restrict__ src,
    const float* __restrict__ Wq, const float* __restrict__ bq,
    const float* __restrict__ Wk, const float* __restrict__ bk,
    const float* __restrict__ Wv, const float* __restrict__ bv,
    float* __restrict__ q, float* __restrict__ k, float* __restrict__ v)
{
  const int row = blockIdx.x;
  const int t = threadIdx.x;
  __shared__ float qs[Dn];
  __shared__ float qrow[Dn];
  if (t < Dn) qs[t] = src[row*Dn + (t%5)*16 + t/5];
  __syncthreads();
  if (t < Dn){
    const float* wr = Wq + t*Dn;
    float a = bq[t];
    #pragma unroll 8
    for (int d2=0; d2<Dn; ++d2) a += qs[d2]*wr[d2];
    qrow[t] = a;
    q[row*Dn + t] = a;
  }
  __syncthreads();
  if (t < Dn){
    const float* wk = Wk + t*Dn;
    const float* wv = Wv + t*Dn;
    float ak = bk[t], av = bv[t];
    #pragma unroll 8
    for (int d2=0; d2<Dn; ++d2){ float qq = qrow[d2]; ak += qq*wk[d2]; av += qq*wv[d2]; }
    k[row*Dn + t] = ak;
    v[row*Dn + t] = av;
  }
}

// ---------------- Transformer: attention (PV parallelized over 128 threads) ----------------
__global__ __launch_bounds__(128) void k_attn(
    const float* __restrict__ q, const float* __restrict__ k, const float* __restrict__ v,
    float* __restrict__ o, float* __restrict__ c_out)
{
  const int s1 = blockIdx.x, h = blockIdx.y, bi = blockIdx.z;
  const int s2 = threadIdx.x;
  __shared__ float qf[DKn];
  __shared__ float p[Tn];
  __shared__ float pa[128];
  __shared__ float red_m[2];
  __shared__ float red_s[2];
  if (s2 < DKn) qf[s2] = q[(bi*Tn + s1)*Dn + h*DKn + s2];
  __syncthreads();
  const float* krow = k + (bi*Tn + s2)*Dn + h*DKn;
  float a = 0.f;
  #pragma unroll
  for (int d2=0; d2<DKn; ++d2) a += qf[d2]*krow[d2];
  a *= 0.25f;
  const int wv_id = s2 >> 6;
  float m = a;
  #pragma unroll
  for (int off=32; off>0; off>>=1) m = fmaxf(m, __shfl_xor(m, off));
  if ((s2 & 63) == 0) red_m[wv_id] = m;
  __syncthreads();
  m = fmaxf(red_m[0], red_m[1]);
  float e = __expf(a - m);
  float tot = e;
  #pragma unroll
  for (int off=32; off>0; off>>=1) tot += __shfl_xor(tot, off);
  if ((s2 & 63) == 0) red_s[wv_id] = tot;
  __syncthreads();
  tot = red_s[0] + red_s[1];
  float pv = e / tot;
  p[s2] = pv;
  c_out[((bi*NHn + h)*Tn + s1)*Tn + s2] = pv;
  __syncthreads();
  // PV: thread = (part 0..7, d 0..15); each accumulates 16 j's
  {
    const int d    = s2 & 15;
    const int part = s2 >> 4;
    const float* vcol = v + bi*Tn*Dn + h*DKn + d;
    float acc = 0.f;
    #pragma unroll
    for (int jj=0; jj<16; ++jj){
      const int j2 = part*16 + jj;
      acc += p[j2]*vcol[j2*Dn];
    }
    pa[s2] = acc;
  }
  __syncthreads();
  if (s2 < DKn){
    float acc = 0.f;
    #pragma unroll
    for (int k2=0; k2<8; ++k2) acc += pa[k2*16 + s2];
    o[(bi*Tn + s1)*Dn + h*DKn + s2] = acc;
  }
}

// ---------------- Transformer: fused (Wo+res+LN) -> (FF+res+LN), row-local ----------------
__global__ __launch_bounds__(320) void k_oln_ffln(
    const float* __restrict__ o, const float* __restrict__ Wo, const float* __restrict__ bo,
    const float* __restrict__ W1, const float* __restrict__ b1,
    const float* __restrict__ W2, const float* __restrict__ b2,
    const float* __restrict__ lng, const float* __restrict__ lnb, float* __restrict__ src)
{
  const int row = blockIdx.x;
  const int t = threadIdx.x;
  __shared__ float orow[Dn];
  __shared__ float s1row[Dn];
  __shared__ float h1[FFn];
  __shared__ float red[128];
  if (t < Dn) orow[t] = o[row*Dn + t];
  __syncthreads();
  float val = 0.f;
  if (t < Dn){
    const float* wr = Wo + t*Dn;
    float a = bo[t];
    #pragma unroll 8
    for (int d2=0; d2<Dn; ++d2) a += orow[d2]*wr[d2];
    val = a + src[row*Dn + t];
  }
  if (t < 128) red[t] = (t < Dn) ? val : 0.f;
  __syncthreads();
  for (int s=64; s>0; s>>=1){ if (t < s) red[t] += red[t+s]; __syncthreads(); }
  float mean = red[0] * (1.f/Dn);
  __syncthreads();
  if (t < 128){ float dv = (t < Dn) ? (val - mean) : 0.f; red[t] = dv*dv; }
  __syncthreads();
  for (int s=64; s>0; s>>=1){ if (t < s) red[t] += red[t+s]; __syncthreads(); }
  float rstd = rsqrtf(red[0]*(1.f/Dn) + 1e-5f);
  if (t < Dn) s1row[t] = (val - mean)*rstd*lng[t] + lnb[t];
  __syncthreads();
  {
    const float* wr = W1 + t*Dn;
    float a = b1[t];
    #pragma unroll 8
    for (int d2=0; d2<Dn; ++d2) a += s1row[d2]*wr[d2];
    h1[t] = fmaxf(a, 0.f);
  }
  __syncthreads();
  float val2 = 0.f;
  if (t < Dn){
    const float* wr = W2 + t*FFn;
    float a = b2[t];
    #pragma unroll 8
    for (int d2=0; d2<FFn; ++d2) a += h1[d2]*wr[d2];
    val2 = a + s1row[t];
  }
  if (t < 128) red[t] = (t < Dn) ? val2 : 0.f;
  __syncthreads();
  for (int s=64; s>0; s>>=1){ if (t < s) red[t] += red[t+s]; __syncthreads(); }
  mean = red[0] * (1.f/Dn);
  __syncthreads();
  if (t < 128){ float dv = (t < Dn) ? (val2 - mean) : 0.f; red[t] = dv*dv; }
  __syncthreads();
  for (int s=64; s>0; s>>=1){ if (t < s) red[t] += red[t+s]; __syncthreads(); }
  rstd = rsqrtf(red[0]*(1.f/Dn) + 1e-5f);
  if (t < Dn) src[row*Dn + t] = (val2 - mean)*rstd*lng[t] + lnb[t];
}

// ---------------- BiLSTM gx: 8 timesteps/block, weight read amortized 8x ----------------
// grid (256, 2), block 256. gx[dir][row*256 + g]
template<int IND>
__global__ __launch_bounds__(256) void k_gx8(
    const float* __restrict__ X,
    const float* __restrict__ WihF, const float* __restrict__ bF,
    const float* __restrict__ WihB, const float* __restrict__ bB,
    float* __restrict__ gx)
{
  const int row0 = blockIdx.x * 8;
  const int dir = blockIdx.y;
  const int g = threadIdx.x;
  __shared__ float xs[8][IND];
  #pragma unroll
  for (int rr=0; rr<8; ++rr)
    for (int d2=g; d2<IND; d2+=256) xs[rr][d2] = X[(row0+rr)*IND + d2];
  __syncthreads();
  const float* W  = dir ? WihB : WihF;
  const float* bb = dir ? bB  : bF;
  const float* wr = W + g*IND;
  float acc[8];
  const float b0 = bb[g];
  #pragma unroll
  for (int rr=0; rr<8; ++rr) acc[rr] = b0;
  #pragma unroll 4
  for (int d2=0; d2<IND; d2+=4){
    const float4 wv = *(const float4*)(wr + d2);
    #pragma unroll
    for (int rr=0; rr<8; ++rr){
      acc[rr] += xs[rr][d2]*wv.x + xs[rr][d2+1]*wv.y + xs[rr][d2+2]*wv.z + xs[rr][d2+3]*wv.w;
    }
  }
  float* gxd = gx + dir*(Bn*Tn*256);
  #pragma unroll
  for (int rr=0; rr<8; ++rr) gxd[(row0+rr)*256 + g] = acc[rr];
}

// ---------------- BiLSTM recurrence (round-11 rec5) ----------------
__global__ __launch_bounds__(512)
void k_bilstm_rec5(
    const float* __restrict__ gx,
    const float* __restrict__ WhhF, const float* __restrict__ WhhB,
    float* __restrict__ outp)
{
  const int n = blockIdx.x;
  const int dir = blockIdx.y;
  const int t = threadIdx.x;
  const int half = t >> 8;
  const int r    = t & 255;
  const float* Whh = dir ? WhhB : WhhF;
  DECL8(w, Whh + r*Hn + half*32);
  PIN8(w);

  __shared__ __align__(16) float hb[Hn];
  __shared__ float pa[512];
  if (t < Hn) hb[t] = 0.f;
  float c = 0.f, h = 0.f;
  __syncthreads();

  const float* gxd = gx + dir*(Bn*Tn*256) + n*Tn*256;
  const float4* hb4 = (const float4*)hb;
  const int jbase = half*8;
  const int t0 = dir ? Tn-1 : 0;
  float g0 = half ? 0.f : gxd[t0*256 + r];
  #pragma unroll 1
  for (int step=0; step<Tn; ++step){
    const int tt = dir ? (Tn-1-step) : step;
    int tn = dir ? (Tn-2-step) : (step+1);
    tn = max(0, min(Tn-1, tn));
    const float p0 = half ? 0.f : gxd[tn*256 + r];   // prefetch next step
    float a = g0;
    ACC8(jbase)
    pa[t] = a;
    __syncthreads();
    if (t < Hn){
      const float zi = pa[t    ] + pa[t+256];
      const float zf = pa[t+ 64] + pa[t+320];
      const float zg = pa[t+128] + pa[t+384];
      const float zo = pa[t+192] + pa[t+448];
      c = sigf(zf)*c + sigf(zi)*tanhfast(zg);
      h = sigf(zo)*tanhfast(c);
      hb[t] = h;
      outp[(n*Tn + tt)*128 + dir*Hn + t] = h;
    }
    __syncthreads();
    g0 = p0;
  }
}

// ---------------- Final head ----------------
__global__ __launch_bounds__(128) void k_final(
    const float* __restrict__ out1,
    const float* __restrict__ fc1W, const float* __restrict__ fc1b,
    const float* __restrict__ fc2W, const float* __restrict__ fc2b,
    float* __restrict__ outp)
{
  const int n = blockIdx.x;
  const int t = threadIdx.x;
  __shared__ float r[128];
  __shared__ float a1[64];
  r[t] = fmaxf(out1[(n*Tn + (Tn-1))*128 + t], 0.f);
  __syncthreads();
  if (t < 64){
    const float* wr = fc1W + t*128;
    float a = fc1b[t];
    #pragma unroll 8
    for (int d2=0; d2<128; ++d2) a += r[d2]*wr[d2];
    a1[t] = fmaxf(a, 0.f);
  }
  __syncthreads();
  if (t == 0){
    float a = fc2b[0];
    #pragma unroll 8
    for (int d2=0; d2<64; ++d2) a += a1[d2]*fc2W[d2];
    outp[n] = a;
  }
}

extern "C" void kernel_launch(void* const* d_in, const int* in_sizes, int n_in,
                              void* d_out, int out_size, void* d_ws, size_t ws_size,
                              hipStream_t stream)
{
  const float* x     = (const float*)d_in[0];
  const float* qWih  = (const float*)d_in[1];
  const float* qWhh  = (const float*)d_in[2];
  const float* qb    = (const float*)d_in[3];
  const float* kWih  = (const float*)d_in[4];
  const float* kWhh  = (const float*)d_in[5];
  const float* kb    = (const float*)d_in[6];
  const float* vWih  = (const float*)d_in[7];
  const float* vWhh  = (const float*)d_in[8];
  const float* vb    = (const float*)d_in[9];
  const float* tWq   = (const float*)d_in[10];
  const float* tbq   = (const float*)d_in[11];
  const float* tWk   = (const float*)d_in[12];
  const float* tbk   = (const float*)d_in[13];
  const float* tWv   = (const float*)d_in[14];
  const float* tbv   = (const float*)d_in[15];
  const float* tWo   = (const float*)d_in[16];
  const float* tbo   = (const float*)d_in[17];
  const float* tW1   = (const float*)d_in[18];
  const float* tb1   = (const float*)d_in[19];
  const float* tW2   = (const float*)d_in[20];
  const float* tb2   = (const float*)d_in[21];
  const float* tlng  = (const float*)d_in[22];
  const float* tlnb  = (const float*)d_in[23];
  const float* l0fWih= (const float*)d_in[24];
  const float* l0fWhh= (const float*)d_in[25];
  const float* l0fb  = (const float*)d_in[26];
  const float* l0bWih= (const float*)d_in[27];
  const float* l0bWhh= (const float*)d_in[28];
  const float* l0bb  = (const float*)d_in[29];
  const float* l1fWih= (const float*)d_in[30];
  const float* l1fWhh= (const float*)d_in[31];
  const float* l1fb  = (const float*)d_in[32];
  const float* l1bWih= (const float*)d_in[33];
  const float* l1bWhh= (const float*)d_in[34];
  const float* l1bb  = (const float*)d_in[35];
  const float* fc1W  = (const float*)d_in[36];
  const float* fc1b  = (const float*)d_in[37];
  const float* fc2W  = (const float*)d_in[38];
  const float* fc2b  = (const float*)d_in[39];

  float* ws  = (float*)d_ws;
  float* hq  = ws;
  float* hk  = hq  + 640*64;
  float* hv  = hk  + 640*64;
  float* Wsm = hv  + 640;
  float* src = Wsm + 16*40*40;
  float* q   = src + 16*128*80;
  float* k   = q   + 16*128*80;
  float* v   = k   + 16*128*80;
  float* o   = v   + 16*128*80;
  float* gx  = o   + 16*128*80;
  float* lout0 = gx + 2*16*128*256;
  float* lout1 = lout0 + 16*128*128;

  float* outp  = (float*)d_out;
  float* out_b = outp + 16;
  float* out_c = out_b + 16*40*40;

  k_feat_lstm3<<<1282, 512, 0, stream>>>(x, qWih,qWhh,qb, kWih,kWhh,kb, vWih,vWhh,vb, hq,hk,hv);
  k_featattn<<<640, 64, 0, stream>>>(hq, hk, hv, Wsm, out_b);
  k_build_src<<<2048, 128, 0, stream>>>(x, Wsm, src);
  for (int l=0; l<2; ++l){
    k_qkv<<<2048, 128, 0, stream>>>(src, tWq + l*Dn*Dn, tbq + l*Dn,
                                    tWk + l*Dn*Dn, tbk + l*Dn,
                                    tWv + l*Dn*Dn, tbv + l*Dn, q, k, v);
    k_attn<<<dim3(128,5,16), 128, 0, stream>>>(q, k, v, o, out_c + (size_t)l*16*5*128*128);
    k_oln_ffln<<<2048, 320, 0, stream>>>(o, tWo + l*Dn*Dn, tbo + l*Dn,
                                         tW1 + l*FFn*Dn, tb1 + l*FFn,
                                         tW2 + l*Dn*FFn, tb2 + l*Dn,
                                         tlng + l*Dn, tlnb + l*Dn, src);
  }
  k_gx8<80><<<dim3(256,2), 256, 0, stream>>>(src, l0fWih, l0fb, l0bWih, l0bb, gx);
  k_bilstm_rec5<<<dim3(16,2), 512, 0, stream>>>(gx, l0fWhh, l0bWhh, lout0);
  k_gx8<128><<<dim3(256,2), 256, 0, stream>>>(lout0, l1fWih, l1fb, l1bWih, l1bb, gx);
  k_bilstm_rec5<<<dim3(16,2), 512, 0, stream>>>(gx, l1fWhh, l1bWhh, lout1);
  k_final<<<16, 128, 0, stream>>>(lout1, fc1W, fc1b, fc2W, fc2b, outp);
}

// Round 5
// 681.940 us; speedup vs baseline: 1.0395x; 1.0395x over previous
//
#include <hip/hip_runtime.h>

__device__ __forceinline__ float sigf(float x){ return 1.0f/(1.0f+__expf(-x)); }
__device__ __forceinline__ float tanhfast(float x){ return 1.0f - 2.0f/(__expf(2.0f*x)+1.0f); }

#define Bn 16
#define Tn 128
#define Fn 40
#define Hn 64
#define Dn 80   // 2F
#define NHn 5
#define DKn 16
#define FFn 320

// ---- round-11 macros (rec5) ----
#define LD4(p,i) (((const float4*)(p))[i])
#define DECL8(v, p) \
  float4 v##0=LD4(p,0), v##1=LD4(p,1), v##2=LD4(p,2), v##3=LD4(p,3), \
         v##4=LD4(p,4), v##5=LD4(p,5), v##6=LD4(p,6), v##7=LD4(p,7);
#define PIN4(P) asm volatile("" : "+v"(P.x), "+v"(P.y), "+v"(P.z), "+v"(P.w));
#define PIN8(v) PIN4(v##0) PIN4(v##1) PIN4(v##2) PIN4(v##3) PIN4(v##4) PIN4(v##5) \
  PIN4(v##6) PIN4(v##7)
#define ACC8(base) \
  { const float4 h0=hb4[(base)+0]; a += h0.x*w0.x + h0.y*w0.y + h0.z*w0.z + h0.w*w0.w; } \
  { const float4 h1=hb4[(base)+1]; a += h1.x*w1.x + h1.y*w1.y + h1.z*w1.z + h1.w*w1.w; } \
  { const float4 h2=hb4[(base)+2]; a += h2.x*w2.x + h2.y*w2.y + h2.z*w2.z + h2.w*w2.w; } \
  { const float4 h3=hb4[(base)+3]; a += h3.x*w3.x + h3.y*w3.y + h3.z*w3.z + h3.w*w3.w; } \
  { const float4 h4=hb4[(base)+4]; a += h4.x*w4.x + h4.y*w4.y + h4.z*w4.z + h4.w*w4.w; } \
  { const float4 h5=hb4[(base)+5]; a += h5.x*w5.x + h5.y*w5.y + h5.z*w5.z + h5.w*w5.w; } \
  { const float4 h6=hb4[(base)+6]; a += h6.x*w6.x + h6.y*w6.y + h6.z*w6.z + h6.w*w6.w; } \
  { const float4 h7=hb4[(base)+7]; a += h7.x*w7.x + h7.y*w7.y + h7.z*w7.z + h7.w*w7.w; }

// ---------------- Stage A: per-feature LSTMs (round-14: 2 instances/block) ----------------
// r13 post-mortem: rec5 port removed spills (WRITE 5.4->0.32MB) but stayed 211us
// — the cost is the per-step serial skeleton (2 barriers + LDS latency + 64-lane
// pointwise), not FMA issue (~128cy/SIMD) nor registers. Whh is SHARED across
// all 640 q (and k) instances, so amortize: each block advances 2 instances in
// lockstep — same pinned weights, 2x FMA per barrier, pointwise on 128 lanes,
// skeleton cost per instance halved. Register shape identical to rec5.
__global__ __launch_bounds__(512) void k_feat_lstm4(
    const float* __restrict__ x,
    const float* __restrict__ qWih, const float* __restrict__ qWhh, const float* __restrict__ qb,
    const float* __restrict__ kWih, const float* __restrict__ kWhh, const float* __restrict__ kb,
    const float* __restrict__ vWih, const float* __restrict__ vWhh, const float* __restrict__ vb,
    float* __restrict__ hq, float* __restrict__ hk, float* __restrict__ hv)
{
  const int blk = blockIdx.x;
  const int t = threadIdx.x;          // 0..511
  if (blk >= 640){
    const int inst = (blk - 640)*512 + t;      // v tail: 0..1023, guard to 640
    if (inst >= 640) return;
    const int bi = inst/Fn, f = inst%Fn;
    const float* xp = x + bi*Tn*Fn + f;
    const float wih0=vWih[0], wih1=vWih[1], wih2=vWih[2], wih3=vWih[3];
    const float u0=vWhh[0], u1=vWhh[1], u2=vWhh[2], u3=vWhh[3];
    const float c0=vb[0], c1=vb[1], c2=vb[2], c3=vb[3];
    float h=0.f, c=0.f;
    #pragma unroll 1
    for (int tt=0;tt<Tn;++tt){
      float xt = xp[tt*Fn];
      float zi = xt*wih0 + h*u0 + c0;
      float zf = xt*wih1 + h*u1 + c1;
      float zg = xt*wih2 + h*u2 + c2;
      float zo = xt*wih3 + h*u3 + c3;
      c = sigf(zf)*c + sigf(zi)*tanhfast(zg);
      h = sigf(zo)*tanhfast(c);
    }
    hv[inst] = h;
    return;
  }
  const bool isk = blk >= 320;
  const int inst0 = (isk ? blk-320 : blk)*2;    // first of 2 instances (0..638)
  const float* Whh = isk ? kWhh : qWhh;
  const float* Wih = isk ? kWih : qWih;
  const float* bia = isk ? kb  : qb;
  float* outp = isk ? hk : hq;

  const int half = t >> 8;   // 0: h[0:32), 1: h[32:64)
  const int r    = t & 255;  // gate row (i,f,g,o stacked)
  DECL8(w, Whh + r*Hn + half*32);
  PIN8(w);
  const float wih0 = Wih[r];
  const float bb0  = bia[r];

  __shared__ __align__(16) float hb[2][Hn];
  __shared__ float pa[2][512];
  __shared__ float xls[2][Tn];

  if (t < 256){
    const int il = t >> 7, tt = t & 127;
    const int inst = inst0 + il;
    const int bi = inst/Fn, f = inst%Fn;
    xls[il][tt] = x[(bi*Tn + tt)*Fn + f];
  }
  if (t < 128) hb[t>>6][t&63] = 0.f;
  float c = 0.f, h = 0.f;
  __syncthreads();

  const int jbase = half*8;
  const float4* hb40 = (const float4*)hb[0];
  const float4* hb41 = (const float4*)hb[1];
  #pragma unroll 1
  for (int step=0; step<Tn; ++step){
    float a0 = half ? 0.f : (bb0 + xls[0][step]*wih0);
    float a1 = half ? 0.f : (bb0 + xls[1][step]*wih0);
    { const float4* hb4 = hb40; float a = a0; ACC8(jbase) a0 = a; }
    { const float4* hb4 = hb41; float a = a1; ACC8(jbase) a1 = a; }
    pa[0][t] = a0;
    pa[1][t] = a1;
    __syncthreads();
    if (t < 128){
      const int il = t>>6, j = t&63;
      const float* p = pa[il];
      const float zi = p[j      ] + p[j+256];
      const float zf = p[j+ 64  ] + p[j+320];
      const float zg = p[j+128  ] + p[j+384];
      const float zo = p[j+192  ] + p[j+448];
      c = sigf(zf)*c + sigf(zi)*tanhfast(zg);
      h = sigf(zo)*tanhfast(c);
      hb[il][j] = h;
    }
    __syncthreads();
  }
  if (t < 128) outp[(inst0 + (t>>6))*Hn + (t&63)] = h;
}

// ---------------- Stage B1: feature attention softmax (writes output b) ----------------
__global__ __launch_bounds__(64) void k_featattn(
    const float* __restrict__ hq, const float* __restrict__ hk, const float* __restrict__ hv,
    float* __restrict__ Wsm, float* __restrict__ out_b)
{
  const int blk = blockIdx.x;
  const int bi = blk / Fn, i = blk % Fn;
  const int j = threadIdx.x;
  __shared__ float qrow[Hn];
  qrow[j] = hq[blk*Hn + j];
  __syncthreads();
  float s = -1e30f;
  if (j < Fn){
    const float* krow = hk + (bi*Fn + j)*Hn;
    float a = 0.f;
    #pragma unroll
    for (int h2=0; h2<Hn; ++h2) a += qrow[h2]*krow[h2];
    s = a * 0.125f * hv[bi*Fn + j];
  }
  float m = s;
  #pragma unroll
  for (int off=32; off>0; off>>=1) m = fmaxf(m, __shfl_xor(m, off));
  float e = (j < Fn) ? __expf(s - m) : 0.f;
  float tot = e;
  #pragma unroll
  for (int off=32; off>0; off>>=1) tot += __shfl_xor(tot, off);
  float p = e / tot;
  if (j < Fn){
    Wsm[blk*Fn + j] = p;
    out_b[bi*(Fn*Fn) + j*Fn + i] = p;
  }
}

// ---------------- Stage B2: attn_output + src concat ----------------
__global__ __launch_bounds__(128) void k_build_src(
    const float* __restrict__ x, const float* __restrict__ Wsm, float* __restrict__ src)
{
  const int blk = blockIdx.x;
  const int bi = blk / Tn;
  const int tid = threadIdx.x;
  __shared__ float xrow[Fn];
  if (tid < Fn) xrow[tid] = x[blk*Fn + tid];
  __syncthreads();
  if (tid < Fn){
    src[blk*Dn + tid] = xrow[tid];
  } else if (tid < Dn){
    const int i = tid - Fn;
    const float* wrow = Wsm + (bi*Fn + i)*Fn;
    float a = 0.f;
    #pragma unroll
    for (int j2=0;j2<Fn;++j2) a += xrow[j2]*wrow[j2];
    src[blk*Dn + tid] = a;
  }
}

// ---------------- Transformer: qkv projection ----------------
__global__ __launch_bounds__(128) void k_qkv(
    const float* __restrict__ src,
    const float* __restrict__ Wq, const float* __restrict__ bq,
    const float* __restrict__ Wk, const float* __restrict__ bk,
    const float* __restrict__ Wv, const float* __restrict__ bv,
    float* __restrict__ q, float* __restrict__ k, float* __restrict__ v)
{
  const int row = blockIdx.x;
  const int t = threadIdx.x;
  __shared__ float qs[Dn];
  __shared__ float qrow[Dn];
  if (t < Dn) qs[t] = src[row*Dn + (t%5)*16 + t/5];
  __syncthreads();
  if (t < Dn){
    const float* wr = Wq + t*Dn;
    float a = bq[t];
    #pragma unroll 8
    for (int d2=0; d2<Dn; ++d2) a += qs[d2]*wr[d2];
    qrow[t] = a;
    q[row*Dn + t] = a;
  }
  __syncthreads();
  if (t < Dn){
    const float* wk = Wk + t*Dn;
    const float* wv = Wv + t*Dn;
    float ak = bk[t], av = bv[t];
    #pragma unroll 8
    for (int d2=0; d2<Dn; ++d2){ float qq = qrow[d2]; ak += qq*wk[d2]; av += qq*wv[d2]; }
    k[row*Dn + t] = ak;
    v[row*Dn + t] = av;
  }
}

// ---------------- Transformer: attention (PV parallelized over 128 threads) ----------------
__global__ __launch_bounds__(128) void k_attn(
    const float* __restrict__ q, const float* __restrict__ k, const float* __restrict__ v,
    float* __restrict__ o, float* __restrict__ c_out)
{
  const int s1 = blockIdx.x, h = blockIdx.y, bi = blockIdx.z;
  const int s2 = threadIdx.x;
  __shared__ float qf[DKn];
  __shared__ float p[Tn];
  __shared__ float pa[128];
  __shared__ float red_m[2];
  __shared__ float red_s[2];
  if (s2 < DKn) qf[s2] = q[(bi*Tn + s1)*Dn + h*DKn + s2];
  __syncthreads();
  const float* krow = k + (bi*Tn + s2)*Dn + h*DKn;
  float a = 0.f;
  #pragma unroll
  for (int d2=0; d2<DKn; ++d2) a += qf[d2]*krow[d2];
  a *= 0.25f;
  const int wv_id = s2 >> 6;
  float m = a;
  #pragma unroll
  for (int off=32; off>0; off>>=1) m = fmaxf(m, __shfl_xor(m, off));
  if ((s2 & 63) == 0) red_m[wv_id] = m;
  __syncthreads();
  m = fmaxf(red_m[0], red_m[1]);
  float e = __expf(a - m);
  float tot = e;
  #pragma unroll
  for (int off=32; off>0; off>>=1) tot += __shfl_xor(tot, off);
  if ((s2 & 63) == 0) red_s[wv_id] = tot;
  __syncthreads();
  tot = red_s[0] + red_s[1];
  float pv = e / tot;
  p[s2] = pv;
  c_out[((bi*NHn + h)*Tn + s1)*Tn + s2] = pv;
  __syncthreads();
  // PV: thread = (part 0..7, d 0..15); each accumulates 16 j's
  {
    const int d    = s2 & 15;
    const int part = s2 >> 4;
    const float* vcol = v + bi*Tn*Dn + h*DKn + d;
    float acc = 0.f;
    #pragma unroll
    for (int jj=0; jj<16; ++jj){
      const int j2 = part*16 + jj;
      acc += p[j2]*vcol[j2*Dn];
    }
    pa[s2] = acc;
  }
  __syncthreads();
  if (s2 < DKn){
    float acc = 0.f;
    #pragma unroll
    for (int k2=0; k2<8; ++k2) acc += pa[k2*16 + s2];
    o[(bi*Tn + s1)*Dn + h*DKn + s2] = acc;
  }
}

// ---------------- Transformer: fused (Wo+res+LN) -> (FF+res+LN), row-local ----------------
__global__ __launch_bounds__(320) void k_oln_ffln(
    const float* __restrict__ o, const float* __restrict__ Wo, const float* __restrict__ bo,
    const float* __restrict__ W1, const float* __restrict__ b1,
    const float* __restrict__ W2, const float* __restrict__ b2,
    const float* __restrict__ lng, const float* __restrict__ lnb, float* __restrict__ src)
{
  const int row = blockIdx.x;
  const int t = threadIdx.x;
  __shared__ float orow[Dn];
  __shared__ float s1row[Dn];
  __shared__ float h1[FFn];
  __shared__ float red[128];
  if (t < Dn) orow[t] = o[row*Dn + t];
  __syncthreads();
  float val = 0.f;
  if (t < Dn){
    const float* wr = Wo + t*Dn;
    float a = bo[t];
    #pragma unroll 8
    for (int d2=0; d2<Dn; ++d2) a += orow[d2]*wr[d2];
    val = a + src[row*Dn + t];
  }
  if (t < 128) red[t] = (t < Dn) ? val : 0.f;
  __syncthreads();
  for (int s=64; s>0; s>>=1){ if (t < s) red[t] += red[t+s]; __syncthreads(); }
  float mean = red[0] * (1.f/Dn);
  __syncthreads();
  if (t < 128){ float dv = (t < Dn) ? (val - mean) : 0.f; red[t] = dv*dv; }
  __syncthreads();
  for (int s=64; s>0; s>>=1){ if (t < s) red[t] += red[t+s]; __syncthreads(); }
  float rstd = rsqrtf(red[0]*(1.f/Dn) + 1e-5f);
  if (t < Dn) s1row[t] = (val - mean)*rstd*lng[t] + lnb[t];
  __syncthreads();
  {
    const float* wr = W1 + t*Dn;
    float a = b1[t];
    #pragma unroll 8
    for (int d2=0; d2<Dn; ++d2) a += s1row[d2]*wr[d2];
    h1[t] = fmaxf(a, 0.f);
  }
  __syncthreads();
  float val2 = 0.f;
  if (t < Dn){
    const float* wr = W2 + t*FFn;
    float a = b2[t];
    #pragma unroll 8
    for (int d2=0; d2<FFn; ++d2) a += h1[d2]*wr[d2];
    val2 = a + s1row[t];
  }
  if (t < 128) red[t] = (t < Dn) ? val2 : 0.f;
  __syncthreads();
  for (int s=64; s>0; s>>=1){ if (t < s) red[t] += red[t+s]; __syncthreads(); }
  mean = red[0] * (1.f/Dn);
  __syncthreads();
  if (t < 128){ float dv = (t < Dn) ? (val2 - mean) : 0.f; red[t] = dv*dv; }
  __syncthreads();
  for (int s=64; s>0; s>>=1){ if (t < s) red[t] += red[t+s]; __syncthreads(); }
  rstd = rsqrtf(red[0]*(1.f/Dn) + 1e-5f);
  if (t < Dn) src[row*Dn + t] = (val2 - mean)*rstd*lng[t] + lnb[t];
}

// ---------------- BiLSTM gx: 8 timesteps/block, weight read amortized 8x ----------------
// grid (256, 2), block 256. gx[dir][row*256 + g]
template<int IND>
__global__ __launch_bounds__(256) void k_gx8(
    const float* __restrict__ X,
    const float* __restrict__ WihF, const float* __restrict__ bF,
    const float* __restrict__ WihB, const float* __restrict__ bB,
    float* __restrict__ gx)
{
  const int row0 = blockIdx.x * 8;
  const int dir = blockIdx.y;
  const int g = threadIdx.x;
  __shared__ float xs[8][IND];
  #pragma unroll
  for (int rr=0; rr<8; ++rr)
    for (int d2=g; d2<IND; d2+=256) xs[rr][d2] = X[(row0+rr)*IND + d2];
  __syncthreads();
  const float* W  = dir ? WihB : WihF;
  const float* bb = dir ? bB  : bF;
  const float* wr = W + g*IND;
  float acc[8];
  const float b0 = bb[g];
  #pragma unroll
  for (int rr=0; rr<8; ++rr) acc[rr] = b0;
  #pragma unroll 4
  for (int d2=0; d2<IND; d2+=4){
    const float4 wv = *(const float4*)(wr + d2);
    #pragma unroll
    for (int rr=0; rr<8; ++rr){
      acc[rr] += xs[rr][d2]*wv.x + xs[rr][d2+1]*wv.y + xs[rr][d2+2]*wv.z + xs[rr][d2+3]*wv.w;
    }
  }
  float* gxd = gx + dir*(Bn*Tn*256);
  #pragma unroll
  for (int rr=0; rr<8; ++rr) gxd[(row0+rr)*256 + g] = acc[rr];
}

// ---------------- BiLSTM recurrence (round-11 rec5) ----------------
__global__ __launch_bounds__(512)
void k_bilstm_rec5(
    const float* __restrict__ gx,
    const float* __restrict__ WhhF, const float* __restrict__ WhhB,
    float* __restrict__ outp)
{
  const int n = blockIdx.x;
  const int dir = blockIdx.y;
  const int t = threadIdx.x;
  const int half = t >> 8;
  const int r    = t & 255;
  const float* Whh = dir ? WhhB : WhhF;
  DECL8(w, Whh + r*Hn + half*32);
  PIN8(w);

  __shared__ __align__(16) float hb[Hn];
  __shared__ float pa[512];
  if (t < Hn) hb[t] = 0.f;
  float c = 0.f, h = 0.f;
  __syncthreads();

  const float* gxd = gx + dir*(Bn*Tn*256) + n*Tn*256;
  const float4* hb4 = (const float4*)hb;
  const int jbase = half*8;
  const int t0 = dir ? Tn-1 : 0;
  float g0 = half ? 0.f : gxd[t0*256 + r];
  #pragma unroll 1
  for (int step=0; step<Tn; ++step){
    const int tt = dir ? (Tn-1-step) : step;
    int tn = dir ? (Tn-2-step) : (step+1);
    tn = max(0, min(Tn-1, tn));
    const float p0 = half ? 0.f : gxd[tn*256 + r];   // prefetch next step
    float a = g0;
    ACC8(jbase)
    pa[t] = a;
    __syncthreads();
    if (t < Hn){
      const float zi = pa[t    ] + pa[t+256];
      const float zf = pa[t+ 64] + pa[t+320];
      const float zg = pa[t+128] + pa[t+384];
      const float zo = pa[t+192] + pa[t+448];
      c = sigf(zf)*c + sigf(zi)*tanhfast(zg);
      h = sigf(zo)*tanhfast(c);
      hb[t] = h;
      outp[(n*Tn + tt)*128 + dir*Hn + t] = h;
    }
    __syncthreads();
    g0 = p0;
  }
}

// ---------------- Final head ----------------
__global__ __launch_bounds__(128) void k_final(
    const float* __restrict__ out1,
    const float* __restrict__ fc1W, const float* __restrict__ fc1b,
    const float* __restrict__ fc2W, const float* __restrict__ fc2b,
    float* __restrict__ outp)
{
  const int n = blockIdx.x;
  const int t = threadIdx.x;
  __shared__ float r[128];
  __shared__ float a1[64];
  r[t] = fmaxf(out1[(n*Tn + (Tn-1))*128 + t], 0.f);
  __syncthreads();
  if (t < 64){
    const float* wr = fc1W + t*128;
    float a = fc1b[t];
    #pragma unroll 8
    for (int d2=0; d2<128; ++d2) a += r[d2]*wr[d2];
    a1[t] = fmaxf(a, 0.f);
  }
  __syncthreads();
  if (t == 0){
    float a = fc2b[0];
    #pragma unroll 8
    for (int d2=0; d2<64; ++d2) a += a1[d2]*fc2W[d2];
    outp[n] = a;
  }
}

extern "C" void kernel_launch(void* const* d_in, const int* in_sizes, int n_in,
                              void* d_out, int out_size, void* d_ws, size_t ws_size,
                              hipStream_t stream)
{
  const float* x     = (const float*)d_in[0];
  const float* qWih  = (const float*)d_in[1];
  const float* qWhh  = (const float*)d_in[2];
  const float* qb    = (const float*)d_in[3];
  const float* kWih  = (const float*)d_in[4];
  const float* kWhh  = (const float*)d_in[5];
  const float* kb    = (const float*)d_in[6];
  const float* vWih  = (const float*)d_in[7];
  const float* vWhh  = (const float*)d_in[8];
  const float* vb    = (const float*)d_in[9];
  const float* tWq   = (const float*)d_in[10];
  const float* tbq   = (const float*)d_in[11];
  const float* tWk   = (const float*)d_in[12];
  const float* tbk   = (const float*)d_in[13];
  const float* tWv   = (const float*)d_in[14];
  const float* tbv   = (const float*)d_in[15];
  const float* tWo   = (const float*)d_in[16];
  const float* tbo   = (const float*)d_in[17];
  const float* tW1   = (const float*)d_in[18];
  const float* tb1   = (const float*)d_in[19];
  const float* tW2   = (const float*)d_in[20];
  const float* tb2   = (const float*)d_in[21];
  const float* tlng  = (const float*)d_in[22];
  const float* tlnb  = (const float*)d_in[23];
  const float* l0fWih= (const float*)d_in[24];
  const float* l0fWhh= (const float*)d_in[25];
  const float* l0fb  = (const float*)d_in[26];
  const float* l0bWih= (const float*)d_in[27];
  const float* l0bWhh= (const float*)d_in[28];
  const float* l0bb  = (const float*)d_in[29];
  const float* l1fWih= (const float*)d_in[30];
  const float* l1fWhh= (const float*)d_in[31];
  const float* l1fb  = (const float*)d_in[32];
  const float* l1bWih= (const float*)d_in[33];
  const float* l1bWhh= (const float*)d_in[34];
  const float* l1bb  = (const float*)d_in[35];
  const float* fc1W  = (const float*)d_in[36];
  const float* fc1b  = (const float*)d_in[37];
  const float* fc2W  = (const float*)d_in[38];
  const float* fc2b  = (const float*)d_in[39];

  float* ws  = (float*)d_ws;
  float* hq  = ws;
  float* hk  = hq  + 640*64;
  float* hv  = hk  + 640*64;
  float* Wsm = hv  + 640;
  float* src = Wsm + 16*40*40;
  float* q   = src + 16*128*80;
  float* k   = q   + 16*128*80;
  float* v   = k   + 16*128*80;
  float* o   = v   + 16*128*80;
  float* gx  = o   + 16*128*80;
  float* lout0 = gx + 2*16*128*256;
  float* lout1 = lout0 + 16*128*128;

  float* outp  = (float*)d_out;
  float* out_b = outp + 16;
  float* out_c = out_b + 16*40*40;

  k_feat_lstm4<<<642, 512, 0, stream>>>(x, qWih,qWhh,qb, kWih,kWhh,kb, vWih,vWhh,vb, hq,hk,hv);
  k_featattn<<<640, 64, 0, stream>>>(hq, hk, hv, Wsm, out_b);
  k_build_src<<<2048, 128, 0, stream>>>(x, Wsm, src);
  for (int l=0; l<2; ++l){
    k_qkv<<<2048, 128, 0, stream>>>(src, tWq + l*Dn*Dn, tbq + l*Dn,
                                    tWk + l*Dn*Dn, tbk + l*Dn,
                                    tWv + l*Dn*Dn, tbv + l*Dn, q, k, v);
    k_attn<<<dim3(128,5,16), 128, 0, stream>>>(q, k, v, o, out_c + (size_t)l*16*5*128*128);
    k_oln_ffln<<<2048, 320, 0, stream>>>(o, tWo + l*Dn*Dn, tbo + l*Dn,
                                         tW1 + l*FFn*Dn, tb1 + l*FFn,
                                         tW2 + l*Dn*FFn, tb2 + l*Dn,
                                         tlng + l*Dn, tlnb + l*Dn, src);
  }
  k_gx8<80><<<dim3(256,2), 256, 0, stream>>>(src, l0fWih, l0fb, l0bWih, l0bb, gx);
  k_bilstm_rec5<<<dim3(16,2), 512, 0, stream>>>(gx, l0fWhh, l0bWhh, lout0);
  k_gx8<128><<<dim3(256,2), 256, 0, stream>>>(lout0, l1fWih, l1fb, l1bWih, l1bb, gx);
  k_bilstm_rec5<<<dim3(16,2), 512, 0, stream>>>(gx, l1fWhh, l1bWhh, lout1);
  k_final<<<16, 128, 0, stream>>>(lout1, fc1W, fc1b, fc2W, fc2b, outp);
}

// Round 6
// 681.912 us; speedup vs baseline: 1.0395x; 1.0000x over previous
//
#include <hip/hip_runtime.h>

__device__ __forceinline__ float sigf(float x){ return 1.0f/(1.0f+__expf(-x)); }
__device__ __forceinline__ float tanhfast(float x){ return 1.0f - 2.0f/(__expf(2.0f*x)+1.0f); }

#define Bn 16
#define Tn 128
#define Fn 40
#define Hn 64
#define Dn 80   // 2F
#define NHn 5
#define DKn 16
#define FFn 320

// ---- round-11 macros (rec5) ----
#define LD4(p,i) (((const float4*)(p))[i])
#define DECL8(v, p) \
  float4 v##0=LD4(p,0), v##1=LD4(p,1), v##2=LD4(p,2), v##3=LD4(p,3), \
         v##4=LD4(p,4), v##5=LD4(p,5), v##6=LD4(p,6), v##7=LD4(p,7);
#define PIN4(P) asm volatile("" : "+v"(P.x), "+v"(P.y), "+v"(P.z), "+v"(P.w));
#define PIN8(v) PIN4(v##0) PIN4(v##1) PIN4(v##2) PIN4(v##3) PIN4(v##4) PIN4(v##5) \
  PIN4(v##6) PIN4(v##7)
#define ACC8(base) \
  { const float4 h0=hb4[(base)+0]; a += h0.x*w0.x + h0.y*w0.y + h0.z*w0.z + h0.w*w0.w; } \
  { const float4 h1=hb4[(base)+1]; a += h1.x*w1.x + h1.y*w1.y + h1.z*w1.z + h1.w*w1.w; } \
  { const float4 h2=hb4[(base)+2]; a += h2.x*w2.x + h2.y*w2.y + h2.z*w2.z + h2.w*w2.w; } \
  { const float4 h3=hb4[(base)+3]; a += h3.x*w3.x + h3.y*w3.y + h3.z*w3.z + h3.w*w3.w; } \
  { const float4 h4=hb4[(base)+4]; a += h4.x*w4.x + h4.y*w4.y + h4.z*w4.z + h4.w*w4.w; } \
  { const float4 h5=hb4[(base)+5]; a += h5.x*w5.x + h5.y*w5.y + h5.z*w5.z + h5.w*w5.w; } \
  { const float4 h6=hb4[(base)+6]; a += h6.x*w6.x + h6.y*w6.y + h6.z*w6.z + h6.w*w6.w; } \
  { const float4 h7=hb4[(base)+7]; a += h7.x*w7.x + h7.y*w7.y + h7.z*w7.z + h7.w*w7.w; }

// two-level paste so ".x" never merges with the pasted digit
#define CAT_(a,b) a##b
#define CAT(a,b) CAT_(a,b)
// fused: one h-read feeds BOTH weight rows (2 MACs per h-float — the r14 lever)
#define ACC1P2(va, vb, n, idx, accA, accB) \
  { const float4 hh=hb4[(idx)]; \
    accA += hh.x*CAT(va,n).x + hh.y*CAT(va,n).y + hh.z*CAT(va,n).z + hh.w*CAT(va,n).w; \
    accB += hh.x*CAT(vb,n).x + hh.y*CAT(vb,n).y + hh.z*CAT(vb,n).z + hh.w*CAT(vb,n).w; }
#define ACC8P2(va, vb, base, accA, accB) \
  ACC1P2(va,vb,0,(base)+0,accA,accB) ACC1P2(va,vb,1,(base)+1,accA,accB) \
  ACC1P2(va,vb,2,(base)+2,accA,accB) ACC1P2(va,vb,3,(base)+3,accA,accB) \
  ACC1P2(va,vb,4,(base)+4,accA,accB) ACC1P2(va,vb,5,(base)+5,accA,accB) \
  ACC1P2(va,vb,6,(base)+6,accA,accB) ACC1P2(va,vb,7,(base)+7,accA,accB)

// ---------------- Stage A: per-feature LSTMs (round-15: gate-pair, 2 MAC/float) ----------------
// r14 post-mortem: all prior Stage-A variants are LDS-read-bound at 1 MAC per
// h-float (10.5M ds_read_b128 ~= 180us — matches every measurement). Fix: thread
// owns output unit r + gate-pair (gp0={i,f}, gp1={g,o}) = 2 full weight rows
// (32 pinned float4); each hb4 read feeds both rows -> LDS instrs halved (5.24M).
// Pointwise: gp1 sends tanh(zg),sig(zo) via 2-float exchange; gp0 updates c,h
// in-thread (pa[512] gather round-trip eliminated). 256thr/2-inst blocks,
// grid 643 -> with ~158 VGPR all blocks co-resident (3 blocks/CU).
__global__ __launch_bounds__(256) void k_feat_lstm5(
    const float* __restrict__ x,
    const float* __restrict__ qWih, const float* __restrict__ qWhh, const float* __restrict__ qb,
    const float* __restrict__ kWih, const float* __restrict__ kWhh, const float* __restrict__ kb,
    const float* __restrict__ vWih, const float* __restrict__ vWhh, const float* __restrict__ vb,
    float* __restrict__ hq, float* __restrict__ hk, float* __restrict__ hv)
{
  const int blk = blockIdx.x;
  const int t = threadIdx.x;          // 0..255
  if (blk >= 640){
    const int inst = (blk - 640)*256 + t;      // v tail: 0..767, guard to 640
    if (inst >= 640) return;
    const int bi = inst/Fn, f = inst%Fn;
    const float* xp = x + bi*Tn*Fn + f;
    const float wih0=vWih[0], wih1=vWih[1], wih2=vWih[2], wih3=vWih[3];
    const float u0=vWhh[0], u1=vWhh[1], u2=vWhh[2], u3=vWhh[3];
    const float c0=vb[0], c1=vb[1], c2=vb[2], c3=vb[3];
    float h=0.f, c=0.f;
    #pragma unroll 1
    for (int tt=0;tt<Tn;++tt){
      float xt = xp[tt*Fn];
      float zi = xt*wih0 + h*u0 + c0;
      float zf = xt*wih1 + h*u1 + c1;
      float zg = xt*wih2 + h*u2 + c2;
      float zo = xt*wih3 + h*u3 + c3;
      c = sigf(zf)*c + sigf(zi)*tanhfast(zg);
      h = sigf(zo)*tanhfast(c);
    }
    hv[inst] = h;
    return;
  }
  const bool isk = blk >= 320;
  const int inst0 = (isk ? blk-320 : blk)*2;    // first of 2 instances
  const float* Whh = isk ? kWhh : qWhh;
  const float* Wih = isk ? kWih : qWih;
  const float* bia = isk ? kb  : qb;
  float* outp = isk ? hk : hq;

  const int il = t >> 7;      // instance-local 0..1
  const int tl = t & 127;
  const int gp = tl >> 6;     // 0: gates {i,f}, 1: gates {g,o}
  const int r  = tl & 63;     // output unit
  const int rA = r + gp*128;  // i (gp0) or g (gp1)
  const int rB = rA + 64;     // f (gp0) or o (gp1)
  const float* rpA = Whh + rA*Hn;
  const float* rpB = Whh + rB*Hn;
  DECL8(wal, rpA); DECL8(wah, rpA + 32);
  DECL8(wbl, rpB); DECL8(wbh, rpB + 32);
  PIN8(wal); PIN8(wah); PIN8(wbl); PIN8(wbh);
  const float wihA = Wih[rA], wihB = Wih[rB];
  const float bbA  = bia[rA], bbB  = bia[rB];

  __shared__ __align__(16) float hb[2][Hn];
  __shared__ float ex[2][2][Hn];
  __shared__ float xls[2][Tn];

  { const int inst = inst0 + il;
    const int bi = inst/Fn, f = inst%Fn;
    xls[il][tl] = x[(bi*Tn + tl)*Fn + f]; }     // 256 threads cover 2x128 steps
  if (tl < Hn && gp == 0) hb[il][r] = 0.f;
  float c = 0.f, h = 0.f;
  __syncthreads();

  const float4* hb4 = (const float4*)hb[il];
  #pragma unroll 1
  for (int step=0; step<Tn; ++step){
    const float xt = xls[il][step];
    float aA = bbA + xt*wihA;
    float aB = bbB + xt*wihB;
    ACC8P2(wal, wbl, 0, aA, aB)
    ACC8P2(wah, wbh, 8, aA, aB)
    if (gp){ ex[il][0][r] = tanhfast(aA); ex[il][1][r] = sigf(aB); }
    __syncthreads();
    if (!gp){
      c = sigf(aB)*c + sigf(aA)*ex[il][0][r];
      h = ex[il][1][r]*tanhfast(c);
      hb[il][r] = h;
    }
    __syncthreads();
  }
  if (!gp) outp[(inst0 + il)*Hn + r] = h;
}

// ---------------- Stage B1: feature attention softmax (writes output b) ----------------
__global__ __launch_bounds__(64) void k_featattn(
    const float* __restrict__ hq, const float* __restrict__ hk, const float* __restrict__ hv,
    float* __restrict__ Wsm, float* __restrict__ out_b)
{
  const int blk = blockIdx.x;
  const int bi = blk / Fn, i = blk % Fn;
  const int j = threadIdx.x;
  __shared__ float qrow[Hn];
  qrow[j] = hq[blk*Hn + j];
  __syncthreads();
  float s = -1e30f;
  if (j < Fn){
    const float* krow = hk + (bi*Fn + j)*Hn;
    float a = 0.f;
    #pragma unroll
    for (int h2=0; h2<Hn; ++h2) a += qrow[h2]*krow[h2];
    s = a * 0.125f * hv[bi*Fn + j];
  }
  float m = s;
  #pragma unroll
  for (int off=32; off>0; off>>=1) m = fmaxf(m, __shfl_xor(m, off));
  float e = (j < Fn) ? __expf(s - m) : 0.f;
  float tot = e;
  #pragma unroll
  for (int off=32; off>0; off>>=1) tot += __shfl_xor(tot, off);
  float p = e / tot;
  if (j < Fn){
    Wsm[blk*Fn + j] = p;
    out_b[bi*(Fn*Fn) + j*Fn + i] = p;
  }
}

// ---------------- Stage B2: attn_output + src concat ----------------
__global__ __launch_bounds__(128) void k_build_src(
    const float* __restrict__ x, const float* __restrict__ Wsm, float* __restrict__ src)
{
  const int blk = blockIdx.x;
  const int bi = blk / Tn;
  const int tid = threadIdx.x;
  __shared__ float xrow[Fn];
  if (tid < Fn) xrow[tid] = x[blk*Fn + tid];
  __syncthreads();
  if (tid < Fn){
    src[blk*Dn + tid] = xrow[tid];
  } else if (tid < Dn){
    const int i = tid - Fn;
    const float* wrow = Wsm + (bi*Fn + i)*Fn;
    float a = 0.f;
    #pragma unroll
    for (int j2=0;j2<Fn;++j2) a += xrow[j2]*wrow[j2];
    src[blk*Dn + tid] = a;
  }
}

// ---------------- Transformer: qkv projection ----------------
__global__ __launch_bounds__(128) void k_qkv(
    const float* __restrict__ src,
    const float* __restrict__ Wq, const float* __restrict__ bq,
    const float* __restrict__ Wk, const float* __restrict__ bk,
    const float* __restrict__ Wv, const float* __restrict__ bv,
    float* __restrict__ q, float* __restrict__ k, float* __restrict__ v)
{
  const int row = blockIdx.x;
  const int t = threadIdx.x;
  __shared__ float qs[Dn];
  __shared__ float qrow[Dn];
  if (t < Dn) qs[t] = src[row*Dn + (t%5)*16 + t/5];
  __syncthreads();
  if (t < Dn){
    const float* wr = Wq + t*Dn;
    float a = bq[t];
    #pragma unroll 8
    for (int d2=0; d2<Dn; ++d2) a += qs[d2]*wr[d2];
    qrow[t] = a;
    q[row*Dn + t] = a;
  }
  __syncthreads();
  if (t < Dn){
    const float* wk = Wk + t*Dn;
    const float* wv = Wv + t*Dn;
    float ak = bk[t], av = bv[t];
    #pragma unroll 8
    for (int d2=0; d2<Dn; ++d2){ float qq = qrow[d2]; ak += qq*wk[d2]; av += qq*wv[d2]; }
    k[row*Dn + t] = ak;
    v[row*Dn + t] = av;
  }
}

// ---------------- Transformer: attention (PV parallelized over 128 threads) ----------------
__global__ __launch_bounds__(128) void k_attn(
    const float* __restrict__ q, const float* __restrict__ k, const float* __restrict__ v,
    float* __restrict__ o, float* __restrict__ c_out)
{
  const int s1 = blockIdx.x, h = blockIdx.y, bi = blockIdx.z;
  const int s2 = threadIdx.x;
  __shared__ float qf[DKn];
  __shared__ float p[Tn];
  __shared__ float pa[128];
  __shared__ float red_m[2];
  __shared__ float red_s[2];
  if (s2 < DKn) qf[s2] = q[(bi*Tn + s1)*Dn + h*DKn + s2];
  __syncthreads();
  const float* krow = k + (bi*Tn + s2)*Dn + h*DKn;
  float a = 0.f;
  #pragma unroll
  for (int d2=0; d2<DKn; ++d2) a += qf[d2]*krow[d2];
  a *= 0.25f;
  const int wv_id = s2 >> 6;
  float m = a;
  #pragma unroll
  for (int off=32; off>0; off>>=1) m = fmaxf(m, __shfl_xor(m, off));
  if ((s2 & 63) == 0) red_m[wv_id] = m;
  __syncthreads();
  m = fmaxf(red_m[0], red_m[1]);
  float e = __expf(a - m);
  float tot = e;
  #pragma unroll
  for (int off=32; off>0; off>>=1) tot += __shfl_xor(tot, off);
  if ((s2 & 63) == 0) red_s[wv_id] = tot;
  __syncthreads();
  tot = red_s[0] + red_s[1];
  float pv = e / tot;
  p[s2] = pv;
  c_out[((bi*NHn + h)*Tn + s1)*Tn + s2] = pv;
  __syncthreads();
  // PV: thread = (part 0..7, d 0..15); each accumulates 16 j's
  {
    const int d    = s2 & 15;
    const int part = s2 >> 4;
    const float* vcol = v + bi*Tn*Dn + h*DKn + d;
    float acc = 0.f;
    #pragma unroll
    for (int jj=0; jj<16; ++jj){
      const int j2 = part*16 + jj;
      acc += p[j2]*vcol[j2*Dn];
    }
    pa[s2] = acc;
  }
  __syncthreads();
  if (s2 < DKn){
    float acc = 0.f;
    #pragma unroll
    for (int k2=0; k2<8; ++k2) acc += pa[k2*16 + s2];
    o[(bi*Tn + s1)*Dn + h*DKn + s2] = acc;
  }
}

// ---------------- Transformer: fused (Wo+res+LN) -> (FF+res+LN), row-local ----------------
__global__ __launch_bounds__(320) void k_oln_ffln(
    const float* __restrict__ o, const float* __restrict__ Wo, const float* __restrict__ bo,
    const float* __restrict__ W1, const float* __restrict__ b1,
    const float* __restrict__ W2, const float* __restrict__ b2,
    const float* __restrict__ lng, const float* __restrict__ lnb, float* __restrict__ src)
{
  const int row = blockIdx.x;
  const int t = threadIdx.x;
  __shared__ float orow[Dn];
  __shared__ float s1row[Dn];
  __shared__ float h1[FFn];
  __shared__ float red[128];
  if (t < Dn) orow[t] = o[row*Dn + t];
  __syncthreads();
  float val = 0.f;
  if (t < Dn){
    const float* wr = Wo + t*Dn;
    float a = bo[t];
    #pragma unroll 8
    for (int d2=0; d2<Dn; ++d2) a += orow[d2]*wr[d2];
    val = a + src[row*Dn + t];
  }
  if (t < 128) red[t] = (t < Dn) ? val : 0.f;
  __syncthreads();
  for (int s=64; s>0; s>>=1){ if (t < s) red[t] += red[t+s]; __syncthreads(); }
  float mean = red[0] * (1.f/Dn);
  __syncthreads();
  if (t < 128){ float dv = (t < Dn) ? (val - mean) : 0.f; red[t] = dv*dv; }
  __syncthreads();
  for (int s=64; s>0; s>>=1){ if (t < s) red[t] += red[t+s]; __syncthreads(); }
  float rstd = rsqrtf(red[0]*(1.f/Dn) + 1e-5f);
  if (t < Dn) s1row[t] = (val - mean)*rstd*lng[t] + lnb[t];
  __syncthreads();
  {
    const float* wr = W1 + t*Dn;
    float a = b1[t];
    #pragma unroll 8
    for (int d2=0; d2<Dn; ++d2) a += s1row[d2]*wr[d2];
    h1[t] = fmaxf(a, 0.f);
  }
  __syncthreads();
  float val2 = 0.f;
  if (t < Dn){
    const float* wr = W2 + t*FFn;
    float a = b2[t];
    #pragma unroll 8
    for (int d2=0; d2<FFn; ++d2) a += h1[d2]*wr[d2];
    val2 = a + s1row[t];
  }
  if (t < 128) red[t] = (t < Dn) ? val2 : 0.f;
  __syncthreads();
  for (int s=64; s>0; s>>=1){ if (t < s) red[t] += red[t+s]; __syncthreads(); }
  mean = red[0] * (1.f/Dn);
  __syncthreads();
  if (t < 128){ float dv = (t < Dn) ? (val2 - mean) : 0.f; red[t] = dv*dv; }
  __syncthreads();
  for (int s=64; s>0; s>>=1){ if (t < s) red[t] += red[t+s]; __syncthreads(); }
  rstd = rsqrtf(red[0]*(1.f/Dn) + 1e-5f);
  if (t < Dn) src[row*Dn + t] = (val2 - mean)*rstd*lng[t] + lnb[t];
}

// ---------------- BiLSTM gx: 8 timesteps/block, weight read amortized 8x ----------------
// grid (256, 2), block 256. gx[dir][row*256 + g]
template<int IND>
__global__ __launch_bounds__(256) void k_gx8(
    const float* __restrict__ X,
    const float* __restrict__ WihF, const float* __restrict__ bF,
    const float* __restrict__ WihB, const float* __restrict__ bB,
    float* __restrict__ gx)
{
  const int row0 = blockIdx.x * 8;
  const int dir = blockIdx.y;
  const int g = threadIdx.x;
  __shared__ float xs[8][IND];
  #pragma unroll
  for (int rr=0; rr<8; ++rr)
    for (int d2=g; d2<IND; d2+=256) xs[rr][d2] = X[(row0+rr)*IND + d2];
  __syncthreads();
  const float* W  = dir ? WihB : WihF;
  const float* bb = dir ? bB  : bF;
  const float* wr = W + g*IND;
  float acc[8];
  const float b0 = bb[g];
  #pragma unroll
  for (int rr=0; rr<8; ++rr) acc[rr] = b0;
  #pragma unroll 4
  for (int d2=0; d2<IND; d2+=4){
    const float4 wv = *(const float4*)(wr + d2);
    #pragma unroll
    for (int rr=0; rr<8; ++rr){
      acc[rr] += xs[rr][d2]*wv.x + xs[rr][d2+1]*wv.y + xs[rr][d2+2]*wv.z + xs[rr][d2+3]*wv.w;
    }
  }
  float* gxd = gx + dir*(Bn*Tn*256);
  #pragma unroll
  for (int rr=0; rr<8; ++rr) gxd[(row0+rr)*256 + g] = acc[rr];
}

// ---------------- BiLSTM recurrence (round-11 rec5) ----------------
__global__ __launch_bounds__(512)
void k_bilstm_rec5(
    const float* __restrict__ gx,
    const float* __restrict__ WhhF, const float* __restrict__ WhhB,
    float* __restrict__ outp)
{
  const int n = blockIdx.x;
  const int dir = blockIdx.y;
  const int t = threadIdx.x;
  const int half = t >> 8;
  const int r    = t & 255;
  const float* Whh = dir ? WhhB : WhhF;
  DECL8(w, Whh + r*Hn + half*32);
  PIN8(w);

  __shared__ __align__(16) float hb[Hn];
  __shared__ float pa[512];
  if (t < Hn) hb[t] = 0.f;
  float c = 0.f, h = 0.f;
  __syncthreads();

  const float* gxd = gx + dir*(Bn*Tn*256) + n*Tn*256;
  const float4* hb4 = (const float4*)hb;
  const int jbase = half*8;
  const int t0 = dir ? Tn-1 : 0;
  float g0 = half ? 0.f : gxd[t0*256 + r];
  #pragma unroll 1
  for (int step=0; step<Tn; ++step){
    const int tt = dir ? (Tn-1-step) : step;
    int tn = dir ? (Tn-2-step) : (step+1);
    tn = max(0, min(Tn-1, tn));
    const float p0 = half ? 0.f : gxd[tn*256 + r];   // prefetch next step
    float a = g0;
    ACC8(jbase)
    pa[t] = a;
    __syncthreads();
    if (t < Hn){
      const float zi = pa[t    ] + pa[t+256];
      const float zf = pa[t+ 64] + pa[t+320];
      const float zg = pa[t+128] + pa[t+384];
      const float zo = pa[t+192] + pa[t+448];
      c = sigf(zf)*c + sigf(zi)*tanhfast(zg);
      h = sigf(zo)*tanhfast(c);
      hb[t] = h;
      outp[(n*Tn + tt)*128 + dir*Hn + t] = h;
    }
    __syncthreads();
    g0 = p0;
  }
}

// ---------------- Final head ----------------
__global__ __launch_bounds__(128) void k_final(
    const float* __restrict__ out1,
    const float* __restrict__ fc1W, const float* __restrict__ fc1b,
    const float* __restrict__ fc2W, const float* __restrict__ fc2b,
    float* __restrict__ outp)
{
  const int n = blockIdx.x;
  const int t = threadIdx.x;
  __shared__ float r[128];
  __shared__ float a1[64];
  r[t] = fmaxf(out1[(n*Tn + (Tn-1))*128 + t], 0.f);
  __syncthreads();
  if (t < 64){
    const float* wr = fc1W + t*128;
    float a = fc1b[t];
    #pragma unroll 8
    for (int d2=0; d2<128; ++d2) a += r[d2]*wr[d2];
    a1[t] = fmaxf(a, 0.f);
  }
  __syncthreads();
  if (t == 0){
    float a = fc2b[0];
    #pragma unroll 8
    for (int d2=0; d2<64; ++d2) a += a1[d2]*fc2W[d2];
    outp[n] = a;
  }
}

extern "C" void kernel_launch(void* const* d_in, const int* in_sizes, int n_in,
                              void* d_out, int out_size, void* d_ws, size_t ws_size,
                              hipStream_t stream)
{
  const float* x     = (const float*)d_in[0];
  const float* qWih  = (const float*)d_in[1];
  const float* qWhh  = (const float*)d_in[2];
  const float* qb    = (const float*)d_in[3];
  const float* kWih  = (const float*)d_in[4];
  const float* kWhh  = (const float*)d_in[5];
  const float* kb    = (const float*)d_in[6];
  const float* vWih  = (const float*)d_in[7];
  const float* vWhh  = (const float*)d_in[8];
  const float* vb    = (const float*)d_in[9];
  const float* tWq   = (const float*)d_in[10];
  const float* tbq   = (const float*)d_in[11];
  const float* tWk   = (const float*)d_in[12];
  const float* tbk   = (const float*)d_in[13];
  const float* tWv   = (const float*)d_in[14];
  const float* tbv   = (const float*)d_in[15];
  const float* tWo   = (const float*)d_in[16];
  const float* tbo   = (const float*)d_in[17];
  const float* tW1   = (const float*)d_in[18];
  const float* tb1   = (const float*)d_in[19];
  const float* tW2   = (const float*)d_in[20];
  const float* tb2   = (const float*)d_in[21];
  const float* tlng  = (const float*)d_in[22];
  const float* tlnb  = (const float*)d_in[23];
  const float* l0fWih= (const float*)d_in[24];
  const float* l0fWhh= (const float*)d_in[25];
  const float* l0fb  = (const float*)d_in[26];
  const float* l0bWih= (const float*)d_in[27];
  const float* l0bWhh= (const float*)d_in[28];
  const float* l0bb  = (const float*)d_in[29];
  const float* l1fWih= (const float*)d_in[30];
  const float* l1fWhh= (const float*)d_in[31];
  const float* l1fb  = (const float*)d_in[32];
  const float* l1bWih= (const float*)d_in[33];
  const float* l1bWhh= (const float*)d_in[34];
  const float* l1bb  = (const float*)d_in[35];
  const float* fc1W  = (const float*)d_in[36];
  const float* fc1b  = (const float*)d_in[37];
  const float* fc2W  = (const float*)d_in[38];
  const float* fc2b  = (const float*)d_in[39];

  float* ws  = (float*)d_ws;
  float* hq  = ws;
  float* hk  = hq  + 640*64;
  float* hv  = hk  + 640*64;
  float* Wsm = hv  + 640;
  float* src = Wsm + 16*40*40;
  float* q   = src + 16*128*80;
  float* k   = q   + 16*128*80;
  float* v   = k   + 16*128*80;
  float* o   = v   + 16*128*80;
  float* gx  = o   + 16*128*80;
  float* lout0 = gx + 2*16*128*256;
  float* lout1 = lout0 + 16*128*128;

  float* outp  = (float*)d_out;
  float* out_b = outp + 16;
  float* out_c = out_b + 16*40*40;

  k_feat_lstm5<<<643, 256, 0, stream>>>(x, qWih,qWhh,qb, kWih,kWhh,kb, vWih,vWhh,vb, hq,hk,hv);
  k_featattn<<<640, 64, 0, stream>>>(hq, hk, hv, Wsm, out_b);
  k_build_src<<<2048, 128, 0, stream>>>(x, Wsm, src);
  for (int l=0; l<2; ++l){
    k_qkv<<<2048, 128, 0, stream>>>(src, tWq + l*Dn*Dn, tbq + l*Dn,
                                    tWk + l*Dn*Dn, tbk + l*Dn,
                                    tWv + l*Dn*Dn, tbv + l*Dn, q, k, v);
    k_attn<<<dim3(128,5,16), 128, 0, stream>>>(q, k, v, o, out_c + (size_t)l*16*5*128*128);
    k_oln_ffln<<<2048, 320, 0, stream>>>(o, tWo + l*Dn*Dn, tbo + l*Dn,
                                         tW1 + l*FFn*Dn, tb1 + l*FFn,
                                         tW2 + l*Dn*FFn, tb2 + l*Dn,
                                         tlng + l*Dn, tlnb + l*Dn, src);
  }
  k_gx8<80><<<dim3(256,2), 256, 0, stream>>>(src, l0fWih, l0fb, l0bWih, l0bb, gx);
  k_bilstm_rec5<<<dim3(16,2), 512, 0, stream>>>(gx, l0fWhh, l0bWhh, lout0);
  k_gx8<128><<<dim3(256,2), 256, 0, stream>>>(lout0, l1fWih, l1fb, l1bWih, l1bb, gx);
  k_bilstm_rec5<<<dim3(16,2), 512, 0, stream>>>(gx, l1fWhh, l1bWhh, lout1);
  k_final<<<16, 128, 0, stream>>>(lout1, fc1W, fc1b, fc2W, fc2b, outp);
}

// Round 8
// 674.848 us; speedup vs baseline: 1.0504x; 1.0105x over previous
//
#include <hip/hip_runtime.h>

__device__ __forceinline__ float sigf(float x){ return 1.0f/(1.0f+__expf(-x)); }
__device__ __forceinline__ float tanhfast(float x){ return 1.0f - 2.0f/(__expf(2.0f*x)+1.0f); }

#define Bn 16
#define Tn 128
#define Fn 40
#define Hn 64
#define Dn 80   // 2F
#define NHn 5
#define DKn 16
#define FFn 320

typedef float v2f __attribute__((ext_vector_type(2)));
typedef float v4f __attribute__((ext_vector_type(4)));

// ---- round-11 macros (rec5) ----
#define LD4(p,i) (((const float4*)(p))[i])
#define DECL8(v, p) \
  float4 v##0=LD4(p,0), v##1=LD4(p,1), v##2=LD4(p,2), v##3=LD4(p,3), \
         v##4=LD4(p,4), v##5=LD4(p,5), v##6=LD4(p,6), v##7=LD4(p,7);
#define PIN4(P) asm volatile("" : "+v"(P.x), "+v"(P.y), "+v"(P.z), "+v"(P.w));
#define PIN8(v) PIN4(v##0) PIN4(v##1) PIN4(v##2) PIN4(v##3) PIN4(v##4) PIN4(v##5) \
  PIN4(v##6) PIN4(v##7)
#define ACC8(base) \
  { const float4 h0=hb4[(base)+0]; a += h0.x*w0.x + h0.y*w0.y + h0.z*w0.z + h0.w*w0.w; } \
  { const float4 h1=hb4[(base)+1]; a += h1.x*w1.x + h1.y*w1.y + h1.z*w1.z + h1.w*w1.w; } \
  { const float4 h2=hb4[(base)+2]; a += h2.x*w2.x + h2.y*w2.y + h2.z*w2.z + h2.w*w2.w; } \
  { const float4 h3=hb4[(base)+3]; a += h3.x*w3.x + h3.y*w3.y + h3.z*w3.z + h3.w*w3.w; } \
  { const float4 h4=hb4[(base)+4]; a += h4.x*w4.x + h4.y*w4.y + h4.z*w4.z + h4.w*w4.w; } \
  { const float4 h5=hb4[(base)+5]; a += h5.x*w5.x + h5.y*w5.y + h5.z*w5.z + h5.w*w5.w; } \
  { const float4 h6=hb4[(base)+6]; a += h6.x*w6.x + h6.y*w6.y + h6.z*w6.z + h6.w*w6.w; } \
  { const float4 h7=hb4[(base)+7]; a += h7.x*w7.x + h7.y*w7.y + h7.z*w7.z + h7.w*w7.w; }

// round-16: packed fp32 FMA (VOP3P, 2 MACs/instr/lane) + keep-in-VGPR pin
#define PKFMA(acc, w, h) asm volatile("v_pk_fma_f32 %0, %1, %2, %0" : "+v"(acc) : "v"(w), "v"(h));
#define PINV2(P) asm volatile("" : "+v"(P));

// ---------------- Stage A: per-feature LSTMs (round-16: true-VGPR + pk_fma) ----------------
// r15 post-mortem: gate-pair halved LDS reads but time stuck at 176us.
// VGPR_Count=80 with 128 pinned floats + WRITE_SIZE flat => surplus weights sat
// in AGPRs (unified file); VALU can't source AGPRs -> per-use v_accvgpr_read
// (~82k cy/CU) on top of irreducible FMA issue (164k cy/CU of 274k VALU-busy).
// Fixes: (1) __launch_bounds__(256,1) lifts the reg cap (r12 failed with cap
// TOO LOW; this raises it) so all 128 weight floats are true VGPRs;
// (2) v_pk_fma_f32 halves FMA instruction count (compiler never emits it).
// Same numerics: IEEE f32 FMA, dot reassociated into 2 partial chains.
__global__ __launch_bounds__(256,1) void k_feat_lstm6(
    const float* __restrict__ x,
    const float* __restrict__ qWih, const float* __restrict__ qWhh, const float* __restrict__ qb,
    const float* __restrict__ kWih, const float* __restrict__ kWhh, const float* __restrict__ kb,
    const float* __restrict__ vWih, const float* __restrict__ vWhh, const float* __restrict__ vb,
    float* __restrict__ hq, float* __restrict__ hk, float* __restrict__ hv)
{
  const int blk = blockIdx.x;
  const int t = threadIdx.x;          // 0..255
  if (blk >= 640){
    const int inst = (blk - 640)*256 + t;      // v tail: 0..767, guard to 640
    if (inst >= 640) return;
    const int bi = inst/Fn, f = inst%Fn;
    const float* xp = x + bi*Tn*Fn + f;
    const float wih0=vWih[0], wih1=vWih[1], wih2=vWih[2], wih3=vWih[3];
    const float u0=vWhh[0], u1=vWhh[1], u2=vWhh[2], u3=vWhh[3];
    const float c0=vb[0], c1=vb[1], c2=vb[2], c3=vb[3];
    float h=0.f, c=0.f;
    #pragma unroll 1
    for (int tt=0;tt<Tn;++tt){
      float xt = xp[tt*Fn];
      float zi = xt*wih0 + h*u0 + c0;
      float zf = xt*wih1 + h*u1 + c1;
      float zg = xt*wih2 + h*u2 + c2;
      float zo = xt*wih3 + h*u3 + c3;
      c = sigf(zf)*c + sigf(zi)*tanhfast(zg);
      h = sigf(zo)*tanhfast(c);
    }
    hv[inst] = h;
    return;
  }
  const bool isk = blk >= 320;
  const int inst0 = (isk ? blk-320 : blk)*2;    // first of 2 instances
  const float* Whh = isk ? kWhh : qWhh;
  const float* Wih = isk ? kWih : qWih;
  const float* bia = isk ? kb  : qb;
  float* outp = isk ? hk : hq;

  const int il = t >> 7;      // instance-local 0..1
  const int tl = t & 127;
  const int gp = tl >> 6;     // 0: gates {i,f}, 1: gates {g,o}
  const int r  = tl & 63;     // output unit
  const int rA = r + gp*128;  // i (gp0) or g (gp1)
  const int rB = rA + 64;     // f (gp0) or o (gp1)
  const v4f* rpA = (const v4f*)(Whh + rA*Hn);
  const v4f* rpB = (const v4f*)(Whh + rB*Hn);
  v2f wA[32], wB[32];
  #pragma unroll
  for (int j=0;j<16;++j){
    const v4f a4 = rpA[j], b4 = rpB[j];
    wA[2*j  ] = __builtin_shufflevector(a4,a4,0,1);
    wA[2*j+1] = __builtin_shufflevector(a4,a4,2,3);
    wB[2*j  ] = __builtin_shufflevector(b4,b4,0,1);
    wB[2*j+1] = __builtin_shufflevector(b4,b4,2,3);
  }
  #pragma unroll
  for (int j=0;j<32;++j){ PINV2(wA[j]) PINV2(wB[j]) }
  const float wihA = Wih[rA], wihB = Wih[rB];
  const float bbA  = bia[rA], bbB  = bia[rB];

  __shared__ __align__(16) float hb[2][Hn];
  __shared__ float ex[2][2][Hn];
  __shared__ float xls[2][Tn];

  { const int inst = inst0 + il;
    const int bi = inst/Fn, f = inst%Fn;
    xls[il][tl] = x[(bi*Tn + tl)*Fn + f]; }     // 256 threads cover 2x128 steps
  if (tl < Hn && gp == 0) hb[il][r] = 0.f;
  float c = 0.f, h = 0.f;
  __syncthreads();

  const v4f* hb4 = (const v4f*)hb[il];
  #pragma unroll 1
  for (int step=0; step<Tn; ++step){
    const float xt = xls[il][step];
    v2f accA, accB;
    accA.x = bbA + xt*wihA; accA.y = 0.f;
    accB.x = bbB + xt*wihB; accB.y = 0.f;
    #pragma unroll
    for (int j=0;j<16;++j){
      const v4f hh = hb4[j];
      const v2f hlo = __builtin_shufflevector(hh,hh,0,1);
      const v2f hhi = __builtin_shufflevector(hh,hh,2,3);
      PKFMA(accA, wA[2*j  ], hlo)
      PKFMA(accA, wA[2*j+1], hhi)
      PKFMA(accB, wB[2*j  ], hlo)
      PKFMA(accB, wB[2*j+1], hhi)
    }
    const float aA = accA.x + accA.y;
    const float aB = accB.x + accB.y;
    if (gp){ ex[il][0][r] = tanhfast(aA); ex[il][1][r] = sigf(aB); }
    __syncthreads();
    if (!gp){
      c = sigf(aB)*c + sigf(aA)*ex[il][0][r];
      h = ex[il][1][r]*tanhfast(c);
      hb[il][r] = h;
    }
    __syncthreads();
  }
  if (!gp) outp[(inst0 + il)*Hn + r] = h;
}

// ---------------- Stage B1: feature attention softmax (writes output b) ----------------
__global__ __launch_bounds__(64) void k_featattn(
    const float* __restrict__ hq, const float* __restrict__ hk, const float* __restrict__ hv,
    float* __restrict__ Wsm, float* __restrict__ out_b)
{
  const int blk = blockIdx.x;
  const int bi = blk / Fn, i = blk % Fn;
  const int j = threadIdx.x;
  __shared__ float qrow[Hn];
  qrow[j] = hq[blk*Hn + j];
  __syncthreads();
  float s = -1e30f;
  if (j < Fn){
    const float* krow = hk + (bi*Fn + j)*Hn;
    float a = 0.f;
    #pragma unroll
    for (int h2=0; h2<Hn; ++h2) a += qrow[h2]*krow[h2];
    s = a * 0.125f * hv[bi*Fn + j];
  }
  float m = s;
  #pragma unroll
  for (int off=32; off>0; off>>=1) m = fmaxf(m, __shfl_xor(m, off));
  float e = (j < Fn) ? __expf(s - m) : 0.f;
  float tot = e;
  #pragma unroll
  for (int off=32; off>0; off>>=1) tot += __shfl_xor(tot, off);
  float p = e / tot;
  if (j < Fn){
    Wsm[blk*Fn + j] = p;
    out_b[bi*(Fn*Fn) + j*Fn + i] = p;
  }
}

// ---------------- Stage B2: attn_output + src concat ----------------
__global__ __launch_bounds__(128) void k_build_src(
    const float* __restrict__ x, const float* __restrict__ Wsm, float* __restrict__ src)
{
  const int blk = blockIdx.x;
  const int bi = blk / Tn;
  const int tid = threadIdx.x;
  __shared__ float xrow[Fn];
  if (tid < Fn) xrow[tid] = x[blk*Fn + tid];
  __syncthreads();
  if (tid < Fn){
    src[blk*Dn + tid] = xrow[tid];
  } else if (tid < Dn){
    const int i = tid - Fn;
    const float* wrow = Wsm + (bi*Fn + i)*Fn;
    float a = 0.f;
    #pragma unroll
    for (int j2=0;j2<Fn;++j2) a += xrow[j2]*wrow[j2];
    src[blk*Dn + tid] = a;
  }
}

// ---------------- Transformer: qkv projection ----------------
__global__ __launch_bounds__(128) void k_qkv(
    const float* __restrict__ src,
    const float* __restrict__ Wq, const float* __restrict__ bq,
    const float* __restrict__ Wk, const float* __restrict__ bk,
    const float* __restrict__ Wv, const float* __restrict__ bv,
    float* __restrict__ q, float* __restrict__ k, float* __restrict__ v)
{
  const int row = blockIdx.x;
  const int t = threadIdx.x;
  __shared__ float qs[Dn];
  __shared__ float qrow[Dn];
  if (t < Dn) qs[t] = src[row*Dn + (t%5)*16 + t/5];
  __syncthreads();
  if (t < Dn){
    const float* wr = Wq + t*Dn;
    float a = bq[t];
    #pragma unroll 8
    for (int d2=0; d2<Dn; ++d2) a += qs[d2]*wr[d2];
    qrow[t] = a;
    q[row*Dn + t] = a;
  }
  __syncthreads();
  if (t < Dn){
    const float* wk = Wk + t*Dn;
    const float* wv = Wv + t*Dn;
    float ak = bk[t], av = bv[t];
    #pragma unroll 8
    for (int d2=0; d2<Dn; ++d2){ float qq = qrow[d2]; ak += qq*wk[d2]; av += qq*wv[d2]; }
    k[row*Dn + t] = ak;
    v[row*Dn + t] = av;
  }
}

// ---------------- Transformer: attention (PV parallelized over 128 threads) ----------------
__global__ __launch_bounds__(128) void k_attn(
    const float* __restrict__ q, const float* __restrict__ k, const float* __restrict__ v,
    float* __restrict__ o, float* __restrict__ c_out)
{
  const int s1 = blockIdx.x, h = blockIdx.y, bi = blockIdx.z;
  const int s2 = threadIdx.x;
  __shared__ float qf[DKn];
  __shared__ float p[Tn];
  __shared__ float pa[128];
  __shared__ float red_m[2];
  __shared__ float red_s[2];
  if (s2 < DKn) qf[s2] = q[(bi*Tn + s1)*Dn + h*DKn + s2];
  __syncthreads();
  const float* krow = k + (bi*Tn + s2)*Dn + h*DKn;
  float a = 0.f;
  #pragma unroll
  for (int d2=0; d2<DKn; ++d2) a += qf[d2]*krow[d2];
  a *= 0.25f;
  const int wv_id = s2 >> 6;
  float m = a;
  #pragma unroll
  for (int off=32; off>0; off>>=1) m = fmaxf(m, __shfl_xor(m, off));
  if ((s2 & 63) == 0) red_m[wv_id] = m;
  __syncthreads();
  m = fmaxf(red_m[0], red_m[1]);
  float e = __expf(a - m);
  float tot = e;
  #pragma unroll
  for (int off=32; off>0; off>>=1) tot += __shfl_xor(tot, off);
  if ((s2 & 63) == 0) red_s[wv_id] = tot;
  __syncthreads();
  tot = red_s[0] + red_s[1];
  float pv = e / tot;
  p[s2] = pv;
  c_out[((bi*NHn + h)*Tn + s1)*Tn + s2] = pv;
  __syncthreads();
  // PV: thread = (part 0..7, d 0..15); each accumulates 16 j's
  {
    const int d    = s2 & 15;
    const int part = s2 >> 4;
    const float* vcol = v + bi*Tn*Dn + h*DKn + d;
    float acc = 0.f;
    #pragma unroll
    for (int jj=0; jj<16; ++jj){
      const int j2 = part*16 + jj;
      acc += p[j2]*vcol[j2*Dn];
    }
    pa[s2] = acc;
  }
  __syncthreads();
  if (s2 < DKn){
    float acc = 0.f;
    #pragma unroll
    for (int k2=0; k2<8; ++k2) acc += pa[k2*16 + s2];
    o[(bi*Tn + s1)*Dn + h*DKn + s2] = acc;
  }
}

// ---------------- Transformer: fused (Wo+res+LN) -> (FF+res+LN), row-local ----------------
__global__ __launch_bounds__(320) void k_oln_ffln(
    const float* __restrict__ o, const float* __restrict__ Wo, const float* __restrict__ bo,
    const float* __restrict__ W1, const float* __restrict__ b1,
    const float* __restrict__ W2, const float* __restrict__ b2,
    const float* __restrict__ lng, const float* __restrict__ lnb, float* __restrict__ src)
{
  const int row = blockIdx.x;
  const int t = threadIdx.x;
  __shared__ float orow[Dn];
  __shared__ float s1row[Dn];
  __shared__ float h1[FFn];
  __shared__ float red[128];
  if (t < Dn) orow[t] = o[row*Dn + t];
  __syncthreads();
  float val = 0.f;
  if (t < Dn){
    const float* wr = Wo + t*Dn;
    float a = bo[t];
    #pragma unroll 8
    for (int d2=0; d2<Dn; ++d2) a += orow[d2]*wr[d2];
    val = a + src[row*Dn + t];
  }
  if (t < 128) red[t] = (t < Dn) ? val : 0.f;
  __syncthreads();
  for (int s=64; s>0; s>>=1){ if (t < s) red[t] += red[t+s]; __syncthreads(); }
  float mean = red[0] * (1.f/Dn);
  __syncthreads();
  if (t < 128){ float dv = (t < Dn) ? (val - mean) : 0.f; red[t] = dv*dv; }
  __syncthreads();
  for (int s=64; s>0; s>>=1){ if (t < s) red[t] += red[t+s]; __syncthreads(); }
  float rstd = rsqrtf(red[0]*(1.f/Dn) + 1e-5f);
  if (t < Dn) s1row[t] = (val - mean)*rstd*lng[t] + lnb[t];
  __syncthreads();
  {
    const float* wr = W1 + t*Dn;
    float a = b1[t];
    #pragma unroll 8
    for (int d2=0; d2<Dn; ++d2) a += s1row[d2]*wr[d2];
    h1[t] = fmaxf(a, 0.f);
  }
  __syncthreads();
  float val2 = 0.f;
  if (t < Dn){
    const float* wr = W2 + t*FFn;
    float a = b2[t];
    #pragma unroll 8
    for (int d2=0; d2<FFn; ++d2) a += h1[d2]*wr[d2];
    val2 = a + s1row[t];
  }
  if (t < 128) red[t] = (t < Dn) ? val2 : 0.f;
  __syncthreads();
  for (int s=64; s>0; s>>=1){ if (t < s) red[t] += red[t+s]; __syncthreads(); }
  mean = red[0] * (1.f/Dn);
  __syncthreads();
  if (t < 128){ float dv = (t < Dn) ? (val2 - mean) : 0.f; red[t] = dv*dv; }
  __syncthreads();
  for (int s=64; s>0; s>>=1){ if (t < s) red[t] += red[t+s]; __syncthreads(); }
  rstd = rsqrtf(red[0]*(1.f/Dn) + 1e-5f);
  if (t < Dn) src[row*Dn + t] = (val2 - mean)*rstd*lng[t] + lnb[t];
}

// ---------------- BiLSTM gx: 8 timesteps/block, weight read amortized 8x ----------------
// grid (256, 2), block 256. gx[dir][row*256 + g]
template<int IND>
__global__ __launch_bounds__(256) void k_gx8(
    const float* __restrict__ X,
    const float* __restrict__ WihF, const float* __restrict__ bF,
    const float* __restrict__ WihB, const float* __restrict__ bB,
    float* __restrict__ gx)
{
  const int row0 = blockIdx.x * 8;
  const int dir = blockIdx.y;
  const int g = threadIdx.x;
  __shared__ float xs[8][IND];
  #pragma unroll
  for (int rr=0; rr<8; ++rr)
    for (int d2=g; d2<IND; d2+=256) xs[rr][d2] = X[(row0+rr)*IND + d2];
  __syncthreads();
  const float* W  = dir ? WihB : WihF;
  const float* bb = dir ? bB  : bF;
  const float* wr = W + g*IND;
  float acc[8];
  const float b0 = bb[g];
  #pragma unroll
  for (int rr=0; rr<8; ++rr) acc[rr] = b0;
  #pragma unroll 4
  for (int d2=0; d2<IND; d2+=4){
    const float4 wv = *(const float4*)(wr + d2);
    #pragma unroll
    for (int rr=0; rr<8; ++rr){
      acc[rr] += xs[rr][d2]*wv.x + xs[rr][d2+1]*wv.y + xs[rr][d2+2]*wv.z + xs[rr][d2+3]*wv.w;
    }
  }
  float* gxd = gx + dir*(Bn*Tn*256);
  #pragma unroll
  for (int rr=0; rr<8; ++rr) gxd[(row0+rr)*256 + g] = acc[rr];
}

// ---------------- BiLSTM recurrence (round-11 rec5) ----------------
__global__ __launch_bounds__(512)
void k_bilstm_rec5(
    const float* __restrict__ gx,
    const float* __restrict__ WhhF, const float* __restrict__ WhhB,
    float* __restrict__ outp)
{
  const int n = blockIdx.x;
  const int dir = blockIdx.y;
  const int t = threadIdx.x;
  const int half = t >> 8;
  const int r    = t & 255;
  const float* Whh = dir ? WhhB : WhhF;
  DECL8(w, Whh + r*Hn + half*32);
  PIN8(w);

  __shared__ __align__(16) float hb[Hn];
  __shared__ float pa[512];
  if (t < Hn) hb[t] = 0.f;
  float c = 0.f, h = 0.f;
  __syncthreads();

  const float* gxd = gx + dir*(Bn*Tn*256) + n*Tn*256;
  const float4* hb4 = (const float4*)hb;
  const int jbase = half*8;
  const int t0 = dir ? Tn-1 : 0;
  float g0 = half ? 0.f : gxd[t0*256 + r];
  #pragma unroll 1
  for (int step=0; step<Tn; ++step){
    const int tt = dir ? (Tn-1-step) : step;
    int tn = dir ? (Tn-2-step) : (step+1);
    tn = max(0, min(Tn-1, tn));
    const float p0 = half ? 0.f : gxd[tn*256 + r];   // prefetch next step
    float a = g0;
    ACC8(jbase)
    pa[t] = a;
    __syncthreads();
    if (t < Hn){
      const float zi = pa[t    ] + pa[t+256];
      const float zf = pa[t+ 64] + pa[t+320];
      const float zg = pa[t+128] + pa[t+384];
      const float zo = pa[t+192] + pa[t+448];
      c = sigf(zf)*c + sigf(zi)*tanhfast(zg);
      h = sigf(zo)*tanhfast(c);
      hb[t] = h;
      outp[(n*Tn + tt)*128 + dir*Hn + t] = h;
    }
    __syncthreads();
    g0 = p0;
  }
}

// ---------------- Final head ----------------
__global__ __launch_bounds__(128) void k_final(
    const float* __restrict__ out1,
    const float* __restrict__ fc1W, const float* __restrict__ fc1b,
    const float* __restrict__ fc2W, const float* __restrict__ fc2b,
    float* __restrict__ outp)
{
  const int n = blockIdx.x;
  const int t = threadIdx.x;
  __shared__ float r[128];
  __shared__ float a1[64];
  r[t] = fmaxf(out1[(n*Tn + (Tn-1))*128 + t], 0.f);
  __syncthreads();
  if (t < 64){
    const float* wr = fc1W + t*128;
    float a = fc1b[t];
    #pragma unroll 8
    for (int d2=0; d2<128; ++d2) a += r[d2]*wr[d2];
    a1[t] = fmaxf(a, 0.f);
  }
  __syncthreads();
  if (t == 0){
    float a = fc2b[0];
    #pragma unroll 8
    for (int d2=0; d2<64; ++d2) a += a1[d2]*fc2W[d2];
    outp[n] = a;
  }
}

extern "C" void kernel_launch(void* const* d_in, const int* in_sizes, int n_in,
                              void* d_out, int out_size, void* d_ws, size_t ws_size,
                              hipStream_t stream)
{
  const float* x     = (const float*)d_in[0];
  const float* qWih  = (const float*)d_in[1];
  const float* qWhh  = (const float*)d_in[2];
  const float* qb    = (const float*)d_in[3];
  const float* kWih  = (const float*)d_in[4];
  const float* kWhh  = (const float*)d_in[5];
  const float* kb    = (const float*)d_in[6];
  const float* vWih  = (const float*)d_in[7];
  const float* vWhh  = (const float*)d_in[8];
  const float* vb    = (const float*)d_in[9];
  const float* tWq   = (const float*)d_in[10];
  const float* tbq   = (const float*)d_in[11];
  const float* tWk   = (const float*)d_in[12];
  const float* tbk   = (const float*)d_in[13];
  const float* tWv   = (const float*)d_in[14];
  const float* tbv   = (const float*)d_in[15];
  const float* tWo   = (const float*)d_in[16];
  const float* tbo   = (const float*)d_in[17];
  const float* tW1   = (const float*)d_in[18];
  const float* tb1   = (const float*)d_in[19];
  const float* tW2   = (const float*)d_in[20];
  const float* tb2   = (const float*)d_in[21];
  const float* tlng  = (const float*)d_in[22];
  const float* tlnb  = (const float*)d_in[23];
  const float* l0fWih= (const float*)d_in[24];
  const float* l0fWhh= (const float*)d_in[25];
  const float* l0fb  = (const float*)d_in[26];
  const float* l0bWih= (const float*)d_in[27];
  const float* l0bWhh= (const float*)d_in[28];
  const float* l0bb  = (const float*)d_in[29];
  const float* l1fWih= (const float*)d_in[30];
  const float* l1fWhh= (const float*)d_in[31];
  const float* l1fb  = (const float*)d_in[32];
  const float* l1bWih= (const float*)d_in[33];
  const float* l1bWhh= (const float*)d_in[34];
  const float* l1bb  = (const float*)d_in[35];
  const float* fc1W  = (const float*)d_in[36];
  const float* fc1b  = (const float*)d_in[37];
  const float* fc2W  = (const float*)d_in[38];
  const float* fc2b  = (const float*)d_in[39];

  float* ws  = (float*)d_ws;
  float* hq  = ws;
  float* hk  = hq  + 640*64;
  float* hv  = hk  + 640*64;
  float* Wsm = hv  + 640;
  float* src = Wsm + 16*40*40;
  float* q   = src + 16*128*80;
  float* k   = q   + 16*128*80;
  float* v   = k   + 16*128*80;
  float* o   = v   + 16*128*80;
  float* gx  = o   + 16*128*80;
  float* lout0 = gx + 2*16*128*256;
  float* lout1 = lout0 + 16*128*128;

  float* outp  = (float*)d_out;
  float* out_b = outp + 16;
  float* out_c = out_b + 16*40*40;

  k_feat_lstm6<<<643, 256, 0, stream>>>(x, qWih,qWhh,qb, kWih,kWhh,kb, vWih,vWhh,vb, hq,hk,hv);
  k_featattn<<<640, 64, 0, stream>>>(hq, hk, hv, Wsm, out_b);
  k_build_src<<<2048, 128, 0, stream>>>(x, Wsm, src);
  for (int l=0; l<2; ++l){
    k_qkv<<<2048, 128, 0, stream>>>(src, tWq + l*Dn*Dn, tbq + l*Dn,
                                    tWk + l*Dn*Dn, tbk + l*Dn,
                                    tWv + l*Dn*Dn, tbv + l*Dn, q, k, v);
    k_attn<<<dim3(128,5,16), 128, 0, stream>>>(q, k, v, o, out_c + (size_t)l*16*5*128*128);
    k_oln_ffln<<<2048, 320, 0, stream>>>(o, tWo + l*Dn*Dn, tbo + l*Dn,
                                         tW1 + l*FFn*Dn, tb1 + l*FFn,
                                         tW2 + l*Dn*FFn, tb2 + l*Dn,
                                         tlng + l*Dn, tlnb + l*Dn, src);
  }
  k_gx8<80><<<dim3(256,2), 256, 0, stream>>>(src, l0fWih, l0fb, l0bWih, l0bb, gx);
  k_bilstm_rec5<<<dim3(16,2), 512, 0, stream>>>(gx, l0fWhh, l0bWhh, lout0);
  k_gx8<128><<<dim3(256,2), 256, 0, stream>>>(lout0, l1fWih, l1fb, l1bWih, l1bb, gx);
  k_bilstm_rec5<<<dim3(16,2), 512, 0, stream>>>(gx, l1fWhh, l1bWhh, lout1);
  k_final<<<16, 128, 0, stream>>>(lout1, fc1W, fc1b, fc2W, fc2b, outp);
}